// Round 7
// baseline (424.557 us; speedup 1.0000x reference)
//
#include <hip/hip_runtime.h>
#include <hip/hip_bf16.h>
#include <stdint.h>
#include <stddef.h>

#define N_ 50000
#define E_ 600000
#define F_ 128
#define H_ 128
#define G_ 64
#define P_ 32
#define C_ 10
#define NB_ 49   // scan blocks: ceil(N/1024)

typedef __hip_bfloat16 bf16;
typedef __attribute__((ext_vector_type(8))) short short8;
typedef __attribute__((ext_vector_type(4))) float float4v;

__device__ __forceinline__ unsigned short f2us(float x){ bf16 h = __float2bfloat16(x); return *(unsigned short*)&h; }
__device__ __forceinline__ float blo(unsigned int u){ return __uint_as_float(u<<16); }
__device__ __forceinline__ float bhi(unsigned int u){ return __uint_as_float(u & 0xFFFF0000u); }
__device__ __forceinline__ unsigned int packbf(float lo, float hi){ return ((unsigned int)f2us(hi)<<16) | f2us(lo); }
__device__ __forceinline__ float eluf(float x){ return x>0.f ? x : __expf(x)-1.f; }
__device__ __forceinline__ float bnf(float x,float m,float v,float g,float b){ return (x-m)*rsqrtf(v+1e-5f)*g+b; }
__device__ __forceinline__ float lrelu(float x){ return x>0.f ? x : 0.2f*x; }
__device__ __forceinline__ float expc(float x){ return __expf(fminf(x, 50.f)); }
__device__ __forceinline__ void atomAddF(float* a, float v){ unsafeAtomicAdd(a, v); }

// ---------------- weight prep: per-lane MFMA B-fragment layout ----------------
__global__ __launch_bounds__(256) void k_wprep(const float* __restrict__ W1, const float* __restrict__ Wl,
    const float* __restrict__ Wr, const float* __restrict__ Wg, unsigned short* __restrict__ WT){
  int idx = blockIdx.x*256 + threadIdx.x;
  if(idx >= 6*16384) return;
  int m    = idx >> 14;
  int tile = (idx >> 11) & 7;
  int kc   = (idx >> 9) & 3;
  int lane = (idx >> 3) & 63;
  int j    = idx & 7;
  int k = kc*32 + (lane>>4)*8 + j;
  int n = tile*16 + (lane&15);
  float v;
  if(m==0)      v = W1[k*128+n];
  else if(m==1) v = Wl[k*128+n];
  else if(m==2) v = Wr[k*128+n];
  else          v = Wg[k*384 + (m-3)*128 + n];
  WT[idx] = f2us(v);
}

// vs3[h*128+f] = sum_j Wg[f, h*128+j] * a_src[h,j]  (and vd3 with a_dst)
__global__ __launch_bounds__(384) void k_vprep(const float* __restrict__ Wg, const float* __restrict__ a_src,
    const float* __restrict__ a_dst, float* __restrict__ vs3, float* __restrict__ vd3){
  int t = threadIdx.x;
  if(t >= 384) return;
  int h = t >> 7, f = t & 127;
  const float4* wr = (const float4*)(Wg + (size_t)f*384 + h*128);
  const float4* as = (const float4*)(a_src + h*128);
  const float4* ad = (const float4*)(a_dst + h*128);
  float s = 0.f, d = 0.f;
  #pragma unroll 8
  for(int j=0;j<32;j++){
    float4 wv = wr[j], av = as[j], dv = ad[j];
    s += wv.x*av.x + wv.y*av.y + wv.z*av.z + wv.w*av.w;
    d += wv.x*dv.x + wv.y*dv.y + wv.z*dv.z + wv.w*dv.w;
  }
  vs3[t] = s; vd3[t] = d;
}

// ---------------- MFMA GEMM helpers (LDS-free, sync-free) ----------------
__device__ __forceinline__ void load_Afrag_bf16(const bf16* A, int row, int lane, short8 af[4]){
  const unsigned short* ap = (const unsigned short*)A + (size_t)row*128 + (lane>>4)*8;
  #pragma unroll
  for(int kc=0;kc<4;kc++) af[kc] = *(const short8*)(ap + kc*32);
}
__device__ __forceinline__ void mfma_pass_g(const unsigned short* __restrict__ WB, const short8 af[4],
                                            int lane, float4v acc[8]){
  #pragma unroll
  for(int tile=0;tile<8;tile++){
    #pragma unroll
    for(int kc=0;kc<4;kc++){
      short8 bfv = *(const short8*)(WB + (((tile*4+kc)*64 + lane)<<3));
      acc[tile] = __builtin_amdgcn_mfma_f32_16x16x32_bf16(af[kc], bfv, acc[tile], 0, 0, 0);
    }
  }
}

// h(bf16) = X(f32) @ W1
__global__ __launch_bounds__(256) void k_mm_x(const float* __restrict__ X, const unsigned short* __restrict__ WTg,
                                              bf16* __restrict__ HB){
  const int tid = threadIdx.x, lane = tid&63, w = tid>>6;
  const int row0 = blockIdx.x*64;
  int arow = row0 + w*16 + (lane&15);
  int ar = arow < N_ ? arow : N_-1;
  const float* ap = X + (size_t)ar*128 + (lane>>4)*8;
  short8 af[4];
  #pragma unroll
  for(int kc=0;kc<4;kc++){
    float4 a = *(const float4*)(ap + kc*32);
    float4 b = *(const float4*)(ap + kc*32 + 4);
    short8 v;
    v[0]=(short)f2us(a.x); v[1]=(short)f2us(a.y); v[2]=(short)f2us(a.z); v[3]=(short)f2us(a.w);
    v[4]=(short)f2us(b.x); v[5]=(short)f2us(b.y); v[6]=(short)f2us(b.z); v[7]=(short)f2us(b.w);
    af[kc]=v;
  }
  float4v acc[8];
  #pragma unroll
  for(int t=0;t<8;t++){ acc[t][0]=0.f; acc[t][1]=0.f; acc[t][2]=0.f; acc[t][3]=0.f; }
  mfma_pass_g(WTg, af, lane, acc);
  const int colb = lane&15, q = lane>>4;
  unsigned short* ob = (unsigned short*)HB;
  #pragma unroll
  for(int r=0;r<4;r++){
    int ro = row0 + w*16 + q*4 + r;
    if(ro < N_){
      #pragma unroll
      for(int tile=0;tile<8;tile++)
        ob[(size_t)ro*128 + tile*16 + colb] = f2us(acc[tile][r]);
    }
  }
}

// h2(bf16) = elu(bn2( mean@Wl + h1@Wr + bs )) ; fused GAT logits als4/ald4 = h2 . vs/vd
__global__ __launch_bounds__(256) void k_sage_mm_att(const bf16* __restrict__ MaB, const bf16* __restrict__ H1B,
    const unsigned short* __restrict__ WlF, const unsigned short* __restrict__ WrF,
    const float* __restrict__ bs, const float* __restrict__ g2, const float* __restrict__ be2,
    const float* __restrict__ m2, const float* __restrict__ v2,
    const float* __restrict__ vs3, const float* __restrict__ vd3,
    bf16* __restrict__ H2B, float* __restrict__ als4, float* __restrict__ ald4){
  const int tid = threadIdx.x, lane = tid&63, w = tid>>6;
  const int row0 = blockIdx.x*64;
  int arow = row0 + w*16 + (lane&15);
  int ar = arow < N_ ? arow : N_-1;
  float4v acc[8];
  #pragma unroll
  for(int t=0;t<8;t++){ acc[t][0]=0.f; acc[t][1]=0.f; acc[t][2]=0.f; acc[t][3]=0.f; }
  short8 af[4];
  load_Afrag_bf16(MaB, ar, lane, af);
  mfma_pass_g(WlF, af, lane, acc);
  load_Afrag_bf16(H1B, ar, lane, af);
  mfma_pass_g(WrF, af, lane, acc);

  const int colb = lane&15, q = lane>>4;
  float vsv[24], vdv[24];
  #pragma unroll
  for(int h=0;h<3;h++){
    #pragma unroll
    for(int tile=0;tile<8;tile++){
      vsv[h*8+tile] = vs3[h*128 + tile*16 + colb];
      vdv[h*8+tile] = vd3[h*128 + tile*16 + colb];
    }
  }
  unsigned short* ob = (unsigned short*)H2B;
  #pragma unroll
  for(int tile=0;tile<8;tile++){
    int col = tile*16 + colb;
    float bsv=bs[col], gv=g2[col], bev=be2[col], mv=m2[col], vv=v2[col];
    #pragma unroll
    for(int r=0;r<4;r++){
      int ro = row0 + w*16 + q*4 + r;
      float x = eluf(bnf(acc[tile][r] + bsv, mv, vv, gv, bev));
      acc[tile][r] = x;
      if(ro < N_) ob[(size_t)ro*128 + col] = f2us(x);
    }
  }
  #pragma unroll
  for(int r=0;r<4;r++){
    int ro = row0 + w*16 + q*4 + r;
    #pragma unroll
    for(int h=0;h<3;h++){
      float ps=0.f, pd=0.f;
      #pragma unroll
      for(int tile=0;tile<8;tile++){ ps += acc[tile][r]*vsv[h*8+tile]; pd += acc[tile][r]*vdv[h*8+tile]; }
      #pragma unroll
      for(int o=8;o>0;o>>=1){ ps += __shfl_down(ps,o,16); pd += __shfl_down(pd,o,16); }
      if(colb==0 && ro<N_){ als4[ro*4+h] = ps; ald4[ro*4+h] = pd; }
    }
  }
}

// h3(bf16) = elu(bn3( sum_h U_h @ Wg_h + bg ))  where U = [U0|U1|U2] is N x 384
__global__ __launch_bounds__(256) void k_gat_mm3(const bf16* __restrict__ U, const unsigned short* __restrict__ WgF,
    const float* __restrict__ bg, const float* __restrict__ g3, const float* __restrict__ be3,
    const float* __restrict__ m3, const float* __restrict__ v3, bf16* __restrict__ H3B){
  const int tid = threadIdx.x, lane = tid&63, w = tid>>6;
  const int row0 = blockIdx.x*64;
  int arow = row0 + w*16 + (lane&15);
  int ar = arow < N_ ? arow : N_-1;
  float4v acc[8];
  #pragma unroll
  for(int t=0;t<8;t++){ acc[t][0]=0.f; acc[t][1]=0.f; acc[t][2]=0.f; acc[t][3]=0.f; }
  short8 af[4];
  for(int hh=0; hh<3; hh++){
    const unsigned short* ap = (const unsigned short*)U + (size_t)ar*384 + hh*128 + (lane>>4)*8;
    #pragma unroll
    for(int kc=0;kc<4;kc++) af[kc] = *(const short8*)(ap + kc*32);
    mfma_pass_g(WgF + hh*16384, af, lane, acc);
  }
  const int colb = lane&15, q = lane>>4;
  unsigned short* ob = (unsigned short*)H3B;
  #pragma unroll
  for(int tile=0;tile<8;tile++){
    int col = tile*16 + colb;
    float bgv=bg[col], gv=g3[col], bev=be3[col], mv=m3[col], vv=v3[col];
    #pragma unroll
    for(int r=0;r<4;r++){
      int ro = row0 + w*16 + q*4 + r;
      if(ro < N_){
        float x = acc[tile][r] + bgv;
        __builtin_nontemporal_store(f2us(eluf(bnf(x, mv, vv, gv, bev))),
                                    ob + (size_t)ro*128 + col);
      }
    }
  }
}

// ---------------- CSR build ----------------
__global__ __launch_bounds__(256) void k_count(const int* __restrict__ dst, int* __restrict__ cnt){
  int e = blockIdx.x*256 + threadIdx.x;
  if(e < E_) atomicAdd(&cnt[dst[e]], 1);
}

__global__ __launch_bounds__(1024) void k_scan1(const int* __restrict__ cnt, int* __restrict__ row_ptr,
                                                float* __restrict__ dinv, int* __restrict__ bsum){
  __shared__ int wsum[16];
  const int t = threadIdx.x, lane = t & 63, wid = t >> 6;
  int i = blockIdx.x*1024 + t;
  int v = (i<N_) ? cnt[i] : 0;
  int x = v;
  #pragma unroll
  for(int o=1;o<64;o<<=1){
    int y = __shfl_up(x, o, 64);
    if(lane >= o) x += y;
  }
  if(lane==63) wsum[wid] = x;
  __syncthreads();
  if(wid==0){
    int s = (lane<16) ? wsum[lane] : 0;
    #pragma unroll
    for(int o=1;o<16;o<<=1){
      int y = __shfl_up(s, o, 64);
      if(lane >= o) s += y;
    }
    if(lane<16) wsum[lane] = s;
  }
  __syncthreads();
  int waveoff = (wid>0) ? wsum[wid-1] : 0;
  int incl = waveoff + x;
  if(i<N_){
    row_ptr[i] = incl - v;
    dinv[i] = rsqrtf((float)v + 1.f);
  }
  if(t==1023) bsum[blockIdx.x] = incl;
}

__global__ __launch_bounds__(64) void k_scan2(const int* __restrict__ bsum, int* __restrict__ boff,
                                              int* __restrict__ row_ptr){
  int lane = threadIdx.x;
  int v = (lane < NB_) ? bsum[lane] : 0;
  int x = v;
  #pragma unroll
  for(int o=1;o<64;o<<=1){
    int y = __shfl_up(x, o, 64);
    if(lane >= o) x += y;
  }
  if(lane < NB_) boff[lane] = x - v;
  if(lane == 63) row_ptr[N_] = x;
}

__global__ __launch_bounds__(256) void k_scan3(int* __restrict__ row_ptr, const int* __restrict__ boff,
                                               int* __restrict__ tmp){
  int i = blockIdx.x*256 + threadIdx.x;
  if(i < N_){
    int r = row_ptr[i] + boff[i>>10];
    row_ptr[i] = r;
    tmp[i] = r;
  }
}

__global__ __launch_bounds__(256) void k_scatter(const int* __restrict__ src, const int* __restrict__ dst,
                                                 int* __restrict__ tmp, int* __restrict__ esrc){
  int e = blockIdx.x*256 + threadIdx.x;
  if(e < E_){
    int d = dst[e];
    int pos = atomicAdd(&tmp[d], 1);
    esrc[pos] = src[e];
  }
}

// ---------------- CSR gather kernels ----------------
__global__ __launch_bounds__(256) void k_gcn_gather(const int* __restrict__ row_ptr, const int* __restrict__ esrc,
    const float* __restrict__ dinv, const bf16* __restrict__ HB,
    const float* __restrict__ b1, const float* __restrict__ g1, const float* __restrict__ be1,
    const float* __restrict__ m1, const float* __restrict__ v1, bf16* __restrict__ H1B){
  int n = blockIdx.x*4 + (threadIdx.x>>6);
  int lane = threadIdx.x & 63;
  if(n >= N_) return;
  int beg = row_ptr[n], end = row_ptr[n+1];
  float dn = dinv[n];
  float a0 = 0.f, a1 = 0.f;
  const unsigned short* hb = (const unsigned short*)HB;
  int e = beg;
  for(; e+7 < end; e += 8){
    int s0=esrc[e],s1=esrc[e+1],s2=esrc[e+2],s3=esrc[e+3];
    int s4=esrc[e+4],s5=esrc[e+5],s6=esrc[e+6],s7=esrc[e+7];
    unsigned int h0=*(const unsigned int*)(hb+(size_t)s0*H_+lane*2);
    unsigned int h1=*(const unsigned int*)(hb+(size_t)s1*H_+lane*2);
    unsigned int h2=*(const unsigned int*)(hb+(size_t)s2*H_+lane*2);
    unsigned int h3=*(const unsigned int*)(hb+(size_t)s3*H_+lane*2);
    unsigned int h4=*(const unsigned int*)(hb+(size_t)s4*H_+lane*2);
    unsigned int h5=*(const unsigned int*)(hb+(size_t)s5*H_+lane*2);
    unsigned int h6=*(const unsigned int*)(hb+(size_t)s6*H_+lane*2);
    unsigned int h7=*(const unsigned int*)(hb+(size_t)s7*H_+lane*2);
    float c0=dinv[s0]*dn,c1=dinv[s1]*dn,c2=dinv[s2]*dn,c3=dinv[s3]*dn;
    float c4=dinv[s4]*dn,c5=dinv[s5]*dn,c6=dinv[s6]*dn,c7=dinv[s7]*dn;
    a0 += c0*blo(h0)+c1*blo(h1)+c2*blo(h2)+c3*blo(h3)
        + c4*blo(h4)+c5*blo(h5)+c6*blo(h6)+c7*blo(h7);
    a1 += c0*bhi(h0)+c1*bhi(h1)+c2*bhi(h2)+c3*bhi(h3)
        + c4*bhi(h4)+c5*bhi(h5)+c6*bhi(h6)+c7*bhi(h7);
  }
  for(; e+3 < end; e += 4){
    int s0=esrc[e],s1=esrc[e+1],s2=esrc[e+2],s3=esrc[e+3];
    unsigned int h0=*(const unsigned int*)(hb+(size_t)s0*H_+lane*2);
    unsigned int h1=*(const unsigned int*)(hb+(size_t)s1*H_+lane*2);
    unsigned int h2=*(const unsigned int*)(hb+(size_t)s2*H_+lane*2);
    unsigned int h3=*(const unsigned int*)(hb+(size_t)s3*H_+lane*2);
    float c0=dinv[s0]*dn,c1=dinv[s1]*dn,c2=dinv[s2]*dn,c3=dinv[s3]*dn;
    a0 += c0*blo(h0)+c1*blo(h1)+c2*blo(h2)+c3*blo(h3);
    a1 += c0*bhi(h0)+c1*bhi(h1)+c2*bhi(h2)+c3*bhi(h3);
  }
  for(; e < end; e++){
    int s = esrc[e];
    float c = dinv[s]*dn;
    unsigned int hv = *(const unsigned int*)(hb + (size_t)s*H_ + lane*2);
    a0 += c*blo(hv);
    a1 += c*bhi(hv);
  }
  unsigned int hv = *(const unsigned int*)(hb + (size_t)n*H_ + lane*2);
  int f0 = lane*2, f1 = f0+1;
  float x0 = a0 + blo(hv)*dn*dn + b1[f0];
  float x1 = a1 + bhi(hv)*dn*dn + b1[f1];
  x0 = eluf(bnf(x0, m1[f0], v1[f0], g1[f0], be1[f0]));
  x1 = eluf(bnf(x1, m1[f1], v1[f1], g1[f1], be1[f1]));
  unsigned int o = ((unsigned int)f2us(x1)<<16) | f2us(x0);
  *(unsigned int*)((unsigned short*)H1B + (size_t)n*H_ + lane*2) = o;
}

__global__ __launch_bounds__(256) void k_sage_gather(const int* __restrict__ row_ptr, const int* __restrict__ esrc,
    const bf16* __restrict__ H1B, bf16* __restrict__ MeanB){
  int n = blockIdx.x*4 + (threadIdx.x>>6);
  int lane = threadIdx.x & 63;
  if(n >= N_) return;
  int beg = row_ptr[n], end = row_ptr[n+1];
  float a0 = 0.f, a1 = 0.f;
  const unsigned short* hb = (const unsigned short*)H1B;
  int e = beg;
  for(; e+7 < end; e += 8){
    int s0=esrc[e],s1=esrc[e+1],s2=esrc[e+2],s3=esrc[e+3];
    int s4=esrc[e+4],s5=esrc[e+5],s6=esrc[e+6],s7=esrc[e+7];
    unsigned int h0=*(const unsigned int*)(hb+(size_t)s0*H_+lane*2);
    unsigned int h1=*(const unsigned int*)(hb+(size_t)s1*H_+lane*2);
    unsigned int h2=*(const unsigned int*)(hb+(size_t)s2*H_+lane*2);
    unsigned int h3=*(const unsigned int*)(hb+(size_t)s3*H_+lane*2);
    unsigned int h4=*(const unsigned int*)(hb+(size_t)s4*H_+lane*2);
    unsigned int h5=*(const unsigned int*)(hb+(size_t)s5*H_+lane*2);
    unsigned int h6=*(const unsigned int*)(hb+(size_t)s6*H_+lane*2);
    unsigned int h7=*(const unsigned int*)(hb+(size_t)s7*H_+lane*2);
    a0 += blo(h0)+blo(h1)+blo(h2)+blo(h3)+blo(h4)+blo(h5)+blo(h6)+blo(h7);
    a1 += bhi(h0)+bhi(h1)+bhi(h2)+bhi(h3)+bhi(h4)+bhi(h5)+bhi(h6)+bhi(h7);
  }
  for(; e+3 < end; e += 4){
    int s0=esrc[e],s1=esrc[e+1],s2=esrc[e+2],s3=esrc[e+3];
    unsigned int h0=*(const unsigned int*)(hb+(size_t)s0*H_+lane*2);
    unsigned int h1=*(const unsigned int*)(hb+(size_t)s1*H_+lane*2);
    unsigned int h2=*(const unsigned int*)(hb+(size_t)s2*H_+lane*2);
    unsigned int h3=*(const unsigned int*)(hb+(size_t)s3*H_+lane*2);
    a0 += blo(h0)+blo(h1)+blo(h2)+blo(h3);
    a1 += bhi(h0)+bhi(h1)+bhi(h2)+bhi(h3);
  }
  for(; e < end; e++){
    unsigned int hv = *(const unsigned int*)(hb + (size_t)esrc[e]*H_ + lane*2);
    a0 += blo(hv);
    a1 += bhi(hv);
  }
  float inv = 1.f / fmaxf((float)(end-beg), 1.f);
  unsigned int o = ((unsigned int)f2us(a1*inv)<<16) | f2us(a0*inv);
  __builtin_nontemporal_store(o, (unsigned int*)((unsigned short*)MeanB + (size_t)n*H_ + lane*2));
}

// GAT aggregation in h2-space with FUSED edge weights:
// stage idx + als4[idx] per lane, compute 3 exps per lane (3E total), shfl into 8-wide row loop.
__global__ __launch_bounds__(256) void k_gat_agg(const int* __restrict__ row_ptr, const int* __restrict__ esrc,
    const float* __restrict__ als4, const float* __restrict__ ald4,
    const bf16* __restrict__ H2B, bf16* __restrict__ U){
  int n = blockIdx.x*4 + (threadIdx.x>>6);
  int lane = threadIdx.x & 63;
  if(n >= N_) return;
  int beg = row_ptr[n], end = row_ptr[n+1];
  float4 asn = *(const float4*)(als4 + (size_t)n*4);
  float4 adn = *(const float4*)(ald4 + (size_t)n*4);
  float es0 = expc(lrelu(asn.x + adn.x));
  float es1 = expc(lrelu(asn.y + adn.y));
  float es2 = expc(lrelu(asn.z + adn.z));
  const unsigned short* hb = (const unsigned short*)H2B;
  unsigned int xs = *(const unsigned int*)(hb + (size_t)n*H_ + lane*2);
  float x0 = blo(xs), x1 = bhi(xs);
  float den0 = es0, den1 = es1, den2 = es2;
  float a00 = es0*x0, a01 = es0*x1;
  float a10 = es1*x0, a11 = es1*x1;
  float a20 = es2*x0, a21 = es2*x1;
  for(int c = beg; c < end; c += 64){
    int take = end - c; if(take > 64) take = 64;
    int idx = esrc[c + (lane < take ? lane : take-1)];
    float4 asl = *(const float4*)(als4 + (size_t)idx*4);
    float w0l = expc(lrelu(asl.x + adn.x));
    float w1l = expc(lrelu(asl.y + adn.y));
    float w2l = expc(lrelu(asl.z + adn.z));
    int j = 0;
    for(; j+7 < take; j += 8){
      int s0=__shfl(idx,j),  s1=__shfl(idx,j+1), s2=__shfl(idx,j+2), s3=__shfl(idx,j+3);
      int s4=__shfl(idx,j+4),s5=__shfl(idx,j+5), s6=__shfl(idx,j+6), s7=__shfl(idx,j+7);
      unsigned int p0=*(const unsigned int*)(hb+(size_t)s0*H_+lane*2);
      unsigned int p1=*(const unsigned int*)(hb+(size_t)s1*H_+lane*2);
      unsigned int p2=*(const unsigned int*)(hb+(size_t)s2*H_+lane*2);
      unsigned int p3=*(const unsigned int*)(hb+(size_t)s3*H_+lane*2);
      unsigned int p4=*(const unsigned int*)(hb+(size_t)s4*H_+lane*2);
      unsigned int p5=*(const unsigned int*)(hb+(size_t)s5*H_+lane*2);
      unsigned int p6=*(const unsigned int*)(hb+(size_t)s6*H_+lane*2);
      unsigned int p7=*(const unsigned int*)(hb+(size_t)s7*H_+lane*2);
      #pragma unroll
      for(int k=0;k<8;k++){
        float u0=__shfl(w0l,j+k), u1=__shfl(w1l,j+k), u2=__shfl(w2l,j+k);
        unsigned int p = (k==0?p0:k==1?p1:k==2?p2:k==3?p3:k==4?p4:k==5?p5:k==6?p6:p7);
        float q0=blo(p), q1=bhi(p);
        den0+=u0; den1+=u1; den2+=u2;
        a00+=u0*q0; a01+=u0*q1;
        a10+=u1*q0; a11+=u1*q1;
        a20+=u2*q0; a21+=u2*q1;
      }
    }
    for(; j < take; j++){
      int s = __shfl(idx,j);
      float u0=__shfl(w0l,j), u1=__shfl(w1l,j), u2=__shfl(w2l,j);
      unsigned int p = *(const unsigned int*)(hb + (size_t)s*H_ + lane*2);
      float q0 = blo(p), q1 = bhi(p);
      den0 += u0; den1 += u1; den2 += u2;
      a00 += u0*q0; a01 += u0*q1;
      a10 += u1*q0; a11 += u1*q1;
      a20 += u2*q0; a21 += u2*q1;
    }
  }
  float i0 = 1.f/(3.f*den0), i1 = 1.f/(3.f*den1), i2 = 1.f/(3.f*den2);
  unsigned short* ub = (unsigned short*)U;
  size_t ubase = (size_t)n*384 + lane*2;
  __builtin_nontemporal_store(packbf(a00*i0, a01*i0), (unsigned int*)(ub + ubase));
  __builtin_nontemporal_store(packbf(a10*i1, a11*i1), (unsigned int*)(ub + ubase + 128));
  __builtin_nontemporal_store(packbf(a20*i2, a21*i2), (unsigned int*)(ub + ubase + 256));
}

// pure pool over graphs (h3 already activated); also counts graph sizes per segment
#define NPW_ 16
__global__ __launch_bounds__(256) void k_h3pool(const bf16* __restrict__ H3B,
    const int* __restrict__ batch, float* __restrict__ pooled, float* __restrict__ gcnt){
  int wave = blockIdx.x*4 + (threadIdx.x>>6);
  int lane = threadIdx.x & 63;
  int n0 = wave*NPW_;
  if(n0 >= N_) return;
  int n1 = n0 + NPW_; if(n1 > N_) n1 = N_;
  int f0 = lane*2, f1 = f0+1;
  float r0=0.f, r1=0.f;
  int cur = batch[n0];
  int seg = 0;
  for(int n=n0; n<n1; n++){
    int b = batch[n];
    if(b != cur){
      atomAddF(&pooled[cur*H_ + f0], r0);
      atomAddF(&pooled[cur*H_ + f1], r1);
      if(lane==0) atomAddF(&gcnt[cur], (float)seg);
      r0 = 0.f; r1 = 0.f; seg = 0; cur = b;
    }
    unsigned int hv = *(const unsigned int*)((const unsigned short*)H3B + (size_t)n*H_ + lane*2);
    r0 += blo(hv);
    r1 += bhi(hv);
    seg++;
  }
  atomAddF(&pooled[cur*H_ + f0], r0);
  atomAddF(&pooled[cur*H_ + f1], r1);
  if(lane==0) atomAddF(&gcnt[cur], (float)seg);
}

// per-graph head — fp32 output
__global__ __launch_bounds__(128) void k_head(const float* __restrict__ pooledacc, const float* __restrict__ gcnt,
    const float* __restrict__ protos, const float* __restrict__ Wc, const float* __restrict__ bc,
    const float* __restrict__ Wd1, const float* __restrict__ bd1, const float* __restrict__ Wd2, const float* __restrict__ bd2,
    float* __restrict__ out){
  const int g = blockIdx.x, t = threadIdx.x;
  __shared__ float p[128], xn[128], red[128], sims[32], es[32], asg[32], pe[128], t1[256];
  __shared__ float nrm;
  float cg_ = fmaxf(gcnt[g], 1.f);
  p[t] = pooledacc[g*128 + t] / cg_;
  __syncthreads();
  red[t] = p[t]*p[t];
  __syncthreads();
  for(int s=64;s>0;s>>=1){ if(t<s) red[t]+=red[t+s]; __syncthreads(); }
  if(t==0) nrm = fmaxf(sqrtf(red[0]), 1e-8f);
  __syncthreads();
  xn[t] = p[t]/nrm;
  __syncthreads();
  if(t<32){
    float s=0.f, pn=0.f;
    for(int f=0;f<128;f++){ float pv=protos[t*128+f]; s += xn[f]*pv; pn += pv*pv; }
    sims[t] = s / fmaxf(sqrtf(pn), 1e-8f);
  }
  __syncthreads();
  if(t<32){
    float mx=-1e30f;
    for(int j=0;j<32;j++) mx = fmaxf(mx, sims[j]);
    es[t] = __expf(sims[t]-mx);
  }
  __syncthreads();
  if(t<32){
    float sm=0.f;
    for(int j=0;j<32;j++) sm += es[j];
    float a = es[t]/fmaxf(sm,1e-20f);
    asg[t] = a;
    out[8832 + g*32 + t] = a;
  }
  __syncthreads();
  {
    float s=0.f;
    for(int pp=0;pp<32;pp++) s += asg[pp]*protos[pp*128+t];
    pe[t] = s;
    out[640 + g*128 + t] = s;
  }
  __syncthreads();
  if(t<10){
    float s = bc[t];
    for(int f=0;f<128;f++) s += pe[f]*Wc[f*10+t];
    out[g*10 + t] = s;
  }
  for(int j=t;j<256;j+=128){
    float s = bd1[j];
    for(int f=0;f<128;f++) s += p[f]*Wd1[f*256+j];
    t1[j] = fmaxf(s, 0.f);
  }
  __syncthreads();
  {
    float s = bd2[t];
    for(int j=0;j<256;j++) s += t1[j]*Wd2[j*128+t];
    out[10880 + g*128 + t] = s;
  }
}

__global__ void k_sentinel(float* out, float code){
  out[0] = code;
}

extern "C" void kernel_launch(void* const* d_in, const int* in_sizes, int n_in,
                              void* d_out, int out_size, void* d_ws, size_t ws_size,
                              hipStream_t stream){
  const float* X    = (const float*)d_in[0];
  const int*  EI    = (const int*)d_in[1];
  const int*  batch = (const int*)d_in[2];
  const int* src = EI;
  const int* dst = EI + E_;

  int iW1,ib1,iWl,iWr,ibs,iWg,ias,iad,ibg,ipr,iWc,ibc,iWd1,ibd1,iWd2,ibd2;
  int ig1,ibe1,im1,iv1,ig2,ibe2,im2,iv2,ig3,ibe3,im3,iv3;
  if(n_in >= 31 && in_sizes[5] == 128){
    iW1=3; ib1=4; ig1=5; ibe1=6; im1=7; iv1=8;
    iWl=9; iWr=10; ibs=11; ig2=12; ibe2=13; im2=14; iv2=15;
    iWg=16; ias=17; iad=18; ibg=19; ig3=20; ibe3=21; im3=22; iv3=23;
    ipr=24; iWc=25; ibc=26; iWd1=27; ibd1=28; iWd2=29; ibd2=30;
  }else{
    iW1=3; ib1=4; iWl=5; iWr=6; ibs=7; iWg=8; ias=9; iad=10; ibg=11;
    ipr=12; iWc=13; ibc=14; iWd1=15; ibd1=16; iWd2=17; ibd2=18;
    ig1=19; ibe1=20; im1=21; iv1=22; ig2=23; ibe2=24; im2=25; iv2=26;
    ig3=27; ibe3=28; im3=29; iv3=30;
  }
  const float* W1 = (const float*)d_in[iW1];   const float* b1 = (const float*)d_in[ib1];
  const float* Wl = (const float*)d_in[iWl];   const float* Wr = (const float*)d_in[iWr];
  const float* bs = (const float*)d_in[ibs];   const float* Wg = (const float*)d_in[iWg];
  const float* a_src = (const float*)d_in[ias]; const float* a_dst = (const float*)d_in[iad];
  const float* bg = (const float*)d_in[ibg];   const float* protos = (const float*)d_in[ipr];
  const float* Wc = (const float*)d_in[iWc];   const float* bc = (const float*)d_in[ibc];
  const float* Wd1 = (const float*)d_in[iWd1]; const float* bd1 = (const float*)d_in[ibd1];
  const float* Wd2 = (const float*)d_in[iWd2]; const float* bd2 = (const float*)d_in[ibd2];
  const float* g1 = (const float*)d_in[ig1];   const float* be1 = (const float*)d_in[ibe1];
  const float* m1 = (const float*)d_in[im1];   const float* v1 = (const float*)d_in[iv1];
  const float* g2 = (const float*)d_in[ig2];   const float* be2 = (const float*)d_in[ibe2];
  const float* m2 = (const float*)d_in[im2];   const float* v2 = (const float*)d_in[iv2];
  const float* g3 = (const float*)d_in[ig3];   const float* be3 = (const float*)d_in[ibe3];
  const float* m3 = (const float*)d_in[im3];   const float* v3 = (const float*)d_in[iv3];

  const size_t NF = (size_t)N_*H_;
  // ints: cnt(N) + row_ptr(N+4) + tmp(N) + esrc(E) + bsum(64) + boff(64)
  const size_t intN = (size_t)3*N_ + 4 + (size_t)E_ + 128;
  // floats: dinv(N) + als4(4N) + ald4(4N) + pooled(G*H) + gcnt(G) + vs3(384) + vd3(384)
  const size_t fltN = (size_t)9*N_ + G_*H_ + G_ + 768;
  const size_t NEED = NF*2*3 + (size_t)N_*384*2 + intN*4 + fltN*4 + (size_t)6*16384*2;
  if(ws_size < NEED){
    k_sentinel<<<1,1,0,stream>>>((float*)d_out, 1000.f + (float)(ws_size>>20));
    return;
  }
  bf16* RA = (bf16*)d_ws;            // h -> h2
  bf16* RB = RA + NF;                // h1
  bf16* RC = RB + NF;                // mean_nb -> h3
  bf16* U  = RC + NF;                // N x 384 aggregated h2-space (3 heads)
  int*  cnt     = (int*)(U + (size_t)N_*384);
  int*  row_ptr = cnt + N_;
  int*  tmp     = row_ptr + (N_+4);
  int*  esrc    = tmp + N_;
  int*  bsum    = esrc + E_;
  int*  boff    = bsum + 64;
  float* dinv   = (float*)(boff + 64);
  float* als4   = dinv + N_;         // N*4 (16B-aligned)
  float* ald4   = als4 + (size_t)N_*4;
  float* pooled = ald4 + (size_t)N_*4;
  float* gcnt   = pooled + (size_t)G_*H_;
  float* vs3    = gcnt + G_;
  float* vd3    = vs3 + 384;
  unsigned short* WTg = (unsigned short*)(vd3 + 384);

  // ---- weight prep + CSR build ----
  k_wprep<<<(6*16384+255)/256, 256, 0, stream>>>(W1, Wl, Wr, Wg, WTg);
  k_vprep<<<1, 384, 0, stream>>>(Wg, a_src, a_dst, vs3, vd3);
  hipMemsetAsync(cnt, 0, N_*sizeof(int), stream);
  hipMemsetAsync(pooled, 0, (size_t)(G_*H_+G_)*sizeof(float), stream);
  k_count<<<(E_+255)/256, 256, 0, stream>>>(dst, cnt);
  k_scan1<<<NB_, 1024, 0, stream>>>(cnt, row_ptr, dinv, bsum);
  k_scan2<<<1, 64, 0, stream>>>(bsum, boff, row_ptr);
  k_scan3<<<(N_+255)/256, 256, 0, stream>>>(row_ptr, boff, tmp);
  k_scatter<<<(E_+255)/256, 256, 0, stream>>>(src, dst, tmp, esrc);

  const int GB = (N_+3)/4;
  const int MB = (N_+63)/64;
  // ---- GCN ----
  k_mm_x<<<MB, 256, 0, stream>>>(X, WTg, RA);
  k_gcn_gather<<<GB, 256, 0, stream>>>(row_ptr, esrc, dinv, RA, b1, g1, be1, m1, v1, RB);
  // ---- SAGE (+ fused GAT logits) ----
  k_sage_gather<<<GB, 256, 0, stream>>>(row_ptr, esrc, RB, RC);
  k_sage_mm_att<<<MB, 256, 0, stream>>>(RC, RB, WTg + 16384, WTg + 2*16384, bs, g2, be2, m2, v2,
                                        vs3, vd3, RA, als4, ald4);
  // ---- GAT: h2-space aggregation (edge weights fused), then one K=384 GEMM ----
  k_gat_agg<<<GB, 256, 0, stream>>>(row_ptr, esrc, als4, ald4, RA, U);
  k_gat_mm3<<<MB, 256, 0, stream>>>(U, WTg + 3*16384, bg, g3, be3, m3, v3, RC);
  // ---- pool + head ----
  {
    int waves = (N_ + NPW_ - 1)/NPW_;
    int blocks = (waves + 3)/4;
    k_h3pool<<<blocks, 256, 0, stream>>>(RC, batch, pooled, gcnt);
  }
  k_head<<<G_, 128, 0, stream>>>(pooled, gcnt, protos, Wc, bc, Wd1, bd1, Wd2, bd2, (float*)d_out);
}

// Round 9
// 412.713 us; speedup vs baseline: 1.0287x; 1.0287x over previous
//
#include <hip/hip_runtime.h>
#include <hip/hip_bf16.h>
#include <stdint.h>
#include <stddef.h>

#define N_ 50000
#define E_ 600000
#define F_ 128
#define H_ 128
#define G_ 64
#define P_ 32
#define C_ 10
#define NB_ 49   // scan blocks: ceil(N/1024)

typedef __hip_bfloat16 bf16;
typedef __attribute__((ext_vector_type(8))) short short8;
typedef __attribute__((ext_vector_type(4))) float float4v;

__device__ __forceinline__ unsigned short f2us(float x){ bf16 h = __float2bfloat16(x); return *(unsigned short*)&h; }
__device__ __forceinline__ float blo(unsigned int u){ return __uint_as_float(u<<16); }
__device__ __forceinline__ float bhi(unsigned int u){ return __uint_as_float(u & 0xFFFF0000u); }
__device__ __forceinline__ unsigned int packbf(float lo, float hi){ return ((unsigned int)f2us(hi)<<16) | f2us(lo); }
__device__ __forceinline__ float eluf(float x){ return x>0.f ? x : __expf(x)-1.f; }
__device__ __forceinline__ float bnf(float x,float m,float v,float g,float b){ return (x-m)*rsqrtf(v+1e-5f)*g+b; }
__device__ __forceinline__ float lrelu(float x){ return x>0.f ? x : 0.2f*x; }
__device__ __forceinline__ float expc(float x){ return __expf(fminf(x, 50.f)); }
__device__ __forceinline__ void atomAddF(float* a, float v){ unsafeAtomicAdd(a, v); }

// ---------------- weight prep: per-lane MFMA B-fragment layout ----------------
__global__ __launch_bounds__(256) void k_wprep(const float* __restrict__ W1, const float* __restrict__ Wl,
    const float* __restrict__ Wr, const float* __restrict__ Wg, unsigned short* __restrict__ WT){
  int idx = blockIdx.x*256 + threadIdx.x;
  if(idx >= 6*16384) return;
  int m    = idx >> 14;
  int tile = (idx >> 11) & 7;
  int kc   = (idx >> 9) & 3;
  int lane = (idx >> 3) & 63;
  int j    = idx & 7;
  int k = kc*32 + (lane>>4)*8 + j;
  int n = tile*16 + (lane&15);
  float v;
  if(m==0)      v = W1[k*128+n];
  else if(m==1) v = Wl[k*128+n];
  else if(m==2) v = Wr[k*128+n];
  else          v = Wg[k*384 + (m-3)*128 + n];
  WT[idx] = f2us(v);
}

// vs3[h*128+f] = sum_j Wg[f, h*128+j] * a_src[h,j]  (and vd3 with a_dst)
__global__ __launch_bounds__(384) void k_vprep(const float* __restrict__ Wg, const float* __restrict__ a_src,
    const float* __restrict__ a_dst, float* __restrict__ vs3, float* __restrict__ vd3){
  int t = threadIdx.x;
  if(t >= 384) return;
  int h = t >> 7, f = t & 127;
  const float4* wr = (const float4*)(Wg + (size_t)f*384 + h*128);
  const float4* as = (const float4*)(a_src + h*128);
  const float4* ad = (const float4*)(a_dst + h*128);
  float s = 0.f, d = 0.f;
  #pragma unroll 8
  for(int j=0;j<32;j++){
    float4 wv = wr[j], av = as[j], dv = ad[j];
    s += wv.x*av.x + wv.y*av.y + wv.z*av.z + wv.w*av.w;
    d += wv.x*dv.x + wv.y*dv.y + wv.z*dv.z + wv.w*dv.w;
  }
  vs3[t] = s; vd3[t] = d;
}

// ---------------- MFMA GEMM helpers (LDS-free, sync-free) ----------------
__device__ __forceinline__ void load_Afrag_bf16(const bf16* A, int row, int lane, short8 af[4]){
  const unsigned short* ap = (const unsigned short*)A + (size_t)row*128 + (lane>>4)*8;
  #pragma unroll
  for(int kc=0;kc<4;kc++) af[kc] = *(const short8*)(ap + kc*32);
}
__device__ __forceinline__ void mfma_pass_g(const unsigned short* __restrict__ WB, const short8 af[4],
                                            int lane, float4v acc[8]){
  #pragma unroll
  for(int tile=0;tile<8;tile++){
    #pragma unroll
    for(int kc=0;kc<4;kc++){
      short8 bfv = *(const short8*)(WB + (((tile*4+kc)*64 + lane)<<3));
      acc[tile] = __builtin_amdgcn_mfma_f32_16x16x32_bf16(af[kc], bfv, acc[tile], 0, 0, 0);
    }
  }
}

// h(bf16) = X(f32) @ W1
__global__ __launch_bounds__(256) void k_mm_x(const float* __restrict__ X, const unsigned short* __restrict__ WTg,
                                              bf16* __restrict__ HB){
  const int tid = threadIdx.x, lane = tid&63, w = tid>>6;
  const int row0 = blockIdx.x*64;
  int arow = row0 + w*16 + (lane&15);
  int ar = arow < N_ ? arow : N_-1;
  const float* ap = X + (size_t)ar*128 + (lane>>4)*8;
  short8 af[4];
  #pragma unroll
  for(int kc=0;kc<4;kc++){
    float4 a = *(const float4*)(ap + kc*32);
    float4 b = *(const float4*)(ap + kc*32 + 4);
    short8 v;
    v[0]=(short)f2us(a.x); v[1]=(short)f2us(a.y); v[2]=(short)f2us(a.z); v[3]=(short)f2us(a.w);
    v[4]=(short)f2us(b.x); v[5]=(short)f2us(b.y); v[6]=(short)f2us(b.z); v[7]=(short)f2us(b.w);
    af[kc]=v;
  }
  float4v acc[8];
  #pragma unroll
  for(int t=0;t<8;t++){ acc[t][0]=0.f; acc[t][1]=0.f; acc[t][2]=0.f; acc[t][3]=0.f; }
  mfma_pass_g(WTg, af, lane, acc);
  const int colb = lane&15, q = lane>>4;
  unsigned short* ob = (unsigned short*)HB;
  #pragma unroll
  for(int r=0;r<4;r++){
    int ro = row0 + w*16 + q*4 + r;
    if(ro < N_){
      #pragma unroll
      for(int tile=0;tile<8;tile++)
        ob[(size_t)ro*128 + tile*16 + colb] = f2us(acc[tile][r]);
    }
  }
}

// h2(bf16) = elu(bn2( mean@Wl + h1@Wr + bs )) ; fused GAT logits als4/ald4 = h2 . vs/vd
__global__ __launch_bounds__(256) void k_sage_mm_att(const bf16* __restrict__ MaB, const bf16* __restrict__ H1B,
    const unsigned short* __restrict__ WlF, const unsigned short* __restrict__ WrF,
    const float* __restrict__ bs, const float* __restrict__ g2, const float* __restrict__ be2,
    const float* __restrict__ m2, const float* __restrict__ v2,
    const float* __restrict__ vs3, const float* __restrict__ vd3,
    bf16* __restrict__ H2B, float* __restrict__ als4, float* __restrict__ ald4){
  const int tid = threadIdx.x, lane = tid&63, w = tid>>6;
  const int row0 = blockIdx.x*64;
  int arow = row0 + w*16 + (lane&15);
  int ar = arow < N_ ? arow : N_-1;
  float4v acc[8];
  #pragma unroll
  for(int t=0;t<8;t++){ acc[t][0]=0.f; acc[t][1]=0.f; acc[t][2]=0.f; acc[t][3]=0.f; }
  short8 af[4];
  load_Afrag_bf16(MaB, ar, lane, af);
  mfma_pass_g(WlF, af, lane, acc);
  load_Afrag_bf16(H1B, ar, lane, af);
  mfma_pass_g(WrF, af, lane, acc);

  const int colb = lane&15, q = lane>>4;
  float vsv[24], vdv[24];
  #pragma unroll
  for(int h=0;h<3;h++){
    #pragma unroll
    for(int tile=0;tile<8;tile++){
      vsv[h*8+tile] = vs3[h*128 + tile*16 + colb];
      vdv[h*8+tile] = vd3[h*128 + tile*16 + colb];
    }
  }
  unsigned short* ob = (unsigned short*)H2B;
  #pragma unroll
  for(int tile=0;tile<8;tile++){
    int col = tile*16 + colb;
    float bsv=bs[col], gv=g2[col], bev=be2[col], mv=m2[col], vv=v2[col];
    #pragma unroll
    for(int r=0;r<4;r++){
      int ro = row0 + w*16 + q*4 + r;
      float x = eluf(bnf(acc[tile][r] + bsv, mv, vv, gv, bev));
      acc[tile][r] = x;
      if(ro < N_) ob[(size_t)ro*128 + col] = f2us(x);
    }
  }
  #pragma unroll
  for(int r=0;r<4;r++){
    int ro = row0 + w*16 + q*4 + r;
    #pragma unroll
    for(int h=0;h<3;h++){
      float ps=0.f, pd=0.f;
      #pragma unroll
      for(int tile=0;tile<8;tile++){ ps += acc[tile][r]*vsv[h*8+tile]; pd += acc[tile][r]*vdv[h*8+tile]; }
      #pragma unroll
      for(int o=8;o>0;o>>=1){ ps += __shfl_down(ps,o,16); pd += __shfl_down(pd,o,16); }
      if(colb==0 && ro<N_){ als4[ro*4+h] = ps; ald4[ro*4+h] = pd; }
    }
  }
}

// h3(bf16) = elu(bn3( sum_h U_h @ Wg_h + bg ))  where U = [U0|U1|U2] is N x 384
__global__ __launch_bounds__(256) void k_gat_mm3(const bf16* __restrict__ U, const unsigned short* __restrict__ WgF,
    const float* __restrict__ bg, const float* __restrict__ g3, const float* __restrict__ be3,
    const float* __restrict__ m3, const float* __restrict__ v3, bf16* __restrict__ H3B){
  const int tid = threadIdx.x, lane = tid&63, w = tid>>6;
  const int row0 = blockIdx.x*64;
  int arow = row0 + w*16 + (lane&15);
  int ar = arow < N_ ? arow : N_-1;
  float4v acc[8];
  #pragma unroll
  for(int t=0;t<8;t++){ acc[t][0]=0.f; acc[t][1]=0.f; acc[t][2]=0.f; acc[t][3]=0.f; }
  short8 af[4];
  for(int hh=0; hh<3; hh++){
    const unsigned short* ap = (const unsigned short*)U + (size_t)ar*384 + hh*128 + (lane>>4)*8;
    #pragma unroll
    for(int kc=0;kc<4;kc++) af[kc] = *(const short8*)(ap + kc*32);
    mfma_pass_g(WgF + hh*16384, af, lane, acc);
  }
  const int colb = lane&15, q = lane>>4;
  unsigned short* ob = (unsigned short*)H3B;
  #pragma unroll
  for(int tile=0;tile<8;tile++){
    int col = tile*16 + colb;
    float bgv=bg[col], gv=g3[col], bev=be3[col], mv=m3[col], vv=v3[col];
    #pragma unroll
    for(int r=0;r<4;r++){
      int ro = row0 + w*16 + q*4 + r;
      if(ro < N_){
        float x = acc[tile][r] + bgv;
        ob[(size_t)ro*128 + col] = f2us(eluf(bnf(x, mv, vv, gv, bev)));
      }
    }
  }
}

// ---------------- CSR build ----------------
__global__ __launch_bounds__(256) void k_count(const int* __restrict__ dst, int* __restrict__ cnt){
  int e = blockIdx.x*256 + threadIdx.x;
  if(e < E_) atomicAdd(&cnt[dst[e]], 1);
}

__global__ __launch_bounds__(1024) void k_scan1(const int* __restrict__ cnt, int* __restrict__ row_ptr,
                                                float* __restrict__ dinv, int* __restrict__ bsum){
  __shared__ int wsum[16];
  const int t = threadIdx.x, lane = t & 63, wid = t >> 6;
  int i = blockIdx.x*1024 + t;
  int v = (i<N_) ? cnt[i] : 0;
  int x = v;
  #pragma unroll
  for(int o=1;o<64;o<<=1){
    int y = __shfl_up(x, o, 64);
    if(lane >= o) x += y;
  }
  if(lane==63) wsum[wid] = x;
  __syncthreads();
  if(wid==0){
    int s = (lane<16) ? wsum[lane] : 0;
    #pragma unroll
    for(int o=1;o<16;o<<=1){
      int y = __shfl_up(s, o, 64);
      if(lane >= o) s += y;
    }
    if(lane<16) wsum[lane] = s;
  }
  __syncthreads();
  int waveoff = (wid>0) ? wsum[wid-1] : 0;
  int incl = waveoff + x;
  if(i<N_){
    row_ptr[i] = incl - v;
    dinv[i] = rsqrtf((float)v + 1.f);
  }
  if(t==1023) bsum[blockIdx.x] = incl;
}

__global__ __launch_bounds__(64) void k_scan2(const int* __restrict__ bsum, int* __restrict__ boff,
                                              int* __restrict__ row_ptr){
  int lane = threadIdx.x;
  int v = (lane < NB_) ? bsum[lane] : 0;
  int x = v;
  #pragma unroll
  for(int o=1;o<64;o<<=1){
    int y = __shfl_up(x, o, 64);
    if(lane >= o) x += y;
  }
  if(lane < NB_) boff[lane] = x - v;
  if(lane == 63) row_ptr[N_] = x;
}

__global__ __launch_bounds__(256) void k_scan3(int* __restrict__ row_ptr, const int* __restrict__ boff,
                                               int* __restrict__ tmp){
  int i = blockIdx.x*256 + threadIdx.x;
  if(i < N_){
    int r = row_ptr[i] + boff[i>>10];
    row_ptr[i] = r;
    tmp[i] = r;
  }
}

__global__ __launch_bounds__(256) void k_scatter(const int* __restrict__ src, const int* __restrict__ dst,
                                                 int* __restrict__ tmp, int* __restrict__ esrc){
  int e = blockIdx.x*256 + threadIdx.x;
  if(e < E_){
    int d = dst[e];
    int pos = atomicAdd(&tmp[d], 1);
    esrc[pos] = src[e];
  }
}

// ---------------- CSR gather kernels: staged indices + split-wave (2 rows per load) ----
// g = lane>>5 selects which of 2 edges this lane serves; c = lane&31 covers 4 bf16
// features at ELEMENT offset c*4 (8 bytes). 32 lanes x 8B = one full 256B row per group.
// Stage idx<<7 (row element offset) + per-edge weights once per 64 edges; weights are 0
// for lanes >= take. Cross-group combine: one shfl_xor(32) (same c in both groups).

__global__ __launch_bounds__(256) void k_gcn_gather(const int* __restrict__ row_ptr, const int* __restrict__ esrc,
    const float* __restrict__ dinv, const bf16* __restrict__ HB,
    const float* __restrict__ b1, const float* __restrict__ g1, const float* __restrict__ be1,
    const float* __restrict__ m1, const float* __restrict__ v1, bf16* __restrict__ H1B){
  int n = blockIdx.x*4 + (threadIdx.x>>6);
  int lane = threadIdx.x & 63;
  if(n >= N_) return;
  const int g = lane>>5, c = lane&31;
  int beg = row_ptr[n], end = row_ptr[n+1];
  float dn = dinv[n];
  const unsigned short* hb = (const unsigned short*)HB;
  uint2 ps = *(const uint2*)(hb + (size_t)n*H_ + c*4);
  float ws = (g==0) ? dn*dn : 0.f;
  float a0 = ws*blo(ps.x), a1 = ws*bhi(ps.x), a2 = ws*blo(ps.y), a3 = ws*bhi(ps.y);
  for(int c0 = beg; c0 < end; c0 += 64){
    int take = end - c0; if(take > 64) take = 64;
    int idx = esrc[c0 + (lane < take ? lane : take-1)];
    float wl = (lane < take) ? dinv[idx]*dn : 0.f;
    int ro = idx << 7;
    int j = 0;
    for(; j+7 < take; j += 8){
      int e0=j+g, e1=j+2+g, e2=j+4+g, e3=j+6+g;
      int r0=__shfl(ro,e0), r1=__shfl(ro,e1), r2=__shfl(ro,e2), r3=__shfl(ro,e3);
      float u0=__shfl(wl,e0), u1=__shfl(wl,e1), u2=__shfl(wl,e2), u3=__shfl(wl,e3);
      uint2 p0 = *(const uint2*)(hb + r0 + c*4);
      uint2 p1 = *(const uint2*)(hb + r1 + c*4);
      uint2 p2 = *(const uint2*)(hb + r2 + c*4);
      uint2 p3 = *(const uint2*)(hb + r3 + c*4);
      a0 += u0*blo(p0.x)+u1*blo(p1.x)+u2*blo(p2.x)+u3*blo(p3.x);
      a1 += u0*bhi(p0.x)+u1*bhi(p1.x)+u2*bhi(p2.x)+u3*bhi(p3.x);
      a2 += u0*blo(p0.y)+u1*blo(p1.y)+u2*blo(p2.y)+u3*blo(p3.y);
      a3 += u0*bhi(p0.y)+u1*bhi(p1.y)+u2*bhi(p2.y)+u3*bhi(p3.y);
    }
    for(; j < take; j += 2){
      int e = j + g;
      int el = e < 64 ? e : 63;
      int r = __shfl(ro, el);
      float u = __shfl(wl, el);
      if(e >= take) u = 0.f;
      uint2 p = *(const uint2*)(hb + r + c*4);
      a0 += u*blo(p.x); a1 += u*bhi(p.x); a2 += u*blo(p.y); a3 += u*bhi(p.y);
    }
  }
  a0 += __shfl_xor(a0,32); a1 += __shfl_xor(a1,32);
  a2 += __shfl_xor(a2,32); a3 += __shfl_xor(a3,32);
  if(g==0){
    float4 bv = *(const float4*)(b1 + c*4);
    float4 mv = *(const float4*)(m1 + c*4);
    float4 vv = *(const float4*)(v1 + c*4);
    float4 gv = *(const float4*)(g1 + c*4);
    float4 ev = *(const float4*)(be1 + c*4);
    uint2 o;
    o.x = packbf(eluf(bnf(a0+bv.x, mv.x, vv.x, gv.x, ev.x)),
                 eluf(bnf(a1+bv.y, mv.y, vv.y, gv.y, ev.y)));
    o.y = packbf(eluf(bnf(a2+bv.z, mv.z, vv.z, gv.z, ev.z)),
                 eluf(bnf(a3+bv.w, mv.w, vv.w, gv.w, ev.w)));
    *(uint2*)((unsigned short*)H1B + (size_t)n*H_ + c*4) = o;
  }
}

__global__ __launch_bounds__(256) void k_sage_gather(const int* __restrict__ row_ptr, const int* __restrict__ esrc,
    const bf16* __restrict__ H1B, bf16* __restrict__ MeanB){
  int n = blockIdx.x*4 + (threadIdx.x>>6);
  int lane = threadIdx.x & 63;
  if(n >= N_) return;
  const int g = lane>>5, c = lane&31;
  int beg = row_ptr[n], end = row_ptr[n+1];
  const unsigned short* hb = (const unsigned short*)H1B;
  float a0=0.f, a1=0.f, a2=0.f, a3=0.f;
  for(int c0 = beg; c0 < end; c0 += 64){
    int take = end - c0; if(take > 64) take = 64;
    int idx = esrc[c0 + (lane < take ? lane : take-1)];
    float wl = (lane < take) ? 1.f : 0.f;
    int ro = idx << 7;
    int j = 0;
    for(; j+7 < take; j += 8){
      int e0=j+g, e1=j+2+g, e2=j+4+g, e3=j+6+g;
      int r0=__shfl(ro,e0), r1=__shfl(ro,e1), r2=__shfl(ro,e2), r3=__shfl(ro,e3);
      float u0=__shfl(wl,e0), u1=__shfl(wl,e1), u2=__shfl(wl,e2), u3=__shfl(wl,e3);
      uint2 p0 = *(const uint2*)(hb + r0 + c*4);
      uint2 p1 = *(const uint2*)(hb + r1 + c*4);
      uint2 p2 = *(const uint2*)(hb + r2 + c*4);
      uint2 p3 = *(const uint2*)(hb + r3 + c*4);
      a0 += u0*blo(p0.x)+u1*blo(p1.x)+u2*blo(p2.x)+u3*blo(p3.x);
      a1 += u0*bhi(p0.x)+u1*bhi(p1.x)+u2*bhi(p2.x)+u3*bhi(p3.x);
      a2 += u0*blo(p0.y)+u1*blo(p1.y)+u2*blo(p2.y)+u3*blo(p3.y);
      a3 += u0*bhi(p0.y)+u1*bhi(p1.y)+u2*bhi(p2.y)+u3*bhi(p3.y);
    }
    for(; j < take; j += 2){
      int e = j + g;
      int el = e < 64 ? e : 63;
      int r = __shfl(ro, el);
      float u = __shfl(wl, el);
      if(e >= take) u = 0.f;
      uint2 p = *(const uint2*)(hb + r + c*4);
      a0 += u*blo(p.x); a1 += u*bhi(p.x); a2 += u*blo(p.y); a3 += u*bhi(p.y);
    }
  }
  a0 += __shfl_xor(a0,32); a1 += __shfl_xor(a1,32);
  a2 += __shfl_xor(a2,32); a3 += __shfl_xor(a3,32);
  if(g==0){
    float inv = 1.f / fmaxf((float)(end-beg), 1.f);
    uint2 o;
    o.x = packbf(a0*inv, a1*inv);
    o.y = packbf(a2*inv, a3*inv);
    *(uint2*)((unsigned short*)MeanB + (size_t)n*H_ + c*4) = o;
  }
}

// GAT aggregation in h2-space, fused edge weights, split-wave inner loop.
__global__ __launch_bounds__(256) void k_gat_agg(const int* __restrict__ row_ptr, const int* __restrict__ esrc,
    const float* __restrict__ als4, const float* __restrict__ ald4,
    const bf16* __restrict__ H2B, bf16* __restrict__ U){
  int n = blockIdx.x*4 + (threadIdx.x>>6);
  int lane = threadIdx.x & 63;
  if(n >= N_) return;
  const int g = lane>>5, c = lane&31;
  int beg = row_ptr[n], end = row_ptr[n+1];
  float4 asn = *(const float4*)(als4 + (size_t)n*4);
  float4 adn = *(const float4*)(ald4 + (size_t)n*4);
  float es0 = expc(lrelu(asn.x + adn.x));
  float es1 = expc(lrelu(asn.y + adn.y));
  float es2 = expc(lrelu(asn.z + adn.z));
  const unsigned short* hb = (const unsigned short*)H2B;
  uint2 ps = *(const uint2*)(hb + (size_t)n*H_ + c*4);
  float w0s = (g==0) ? es0 : 0.f;
  float w1s = (g==0) ? es1 : 0.f;
  float w2s = (g==0) ? es2 : 0.f;
  float f0=blo(ps.x), f1=bhi(ps.x), f2=blo(ps.y), f3=bhi(ps.y);
  float a00=w0s*f0, a01=w0s*f1, a02=w0s*f2, a03=w0s*f3;
  float a10=w1s*f0, a11=w1s*f1, a12=w1s*f2, a13=w1s*f3;
  float a20=w2s*f0, a21=w2s*f1, a22=w2s*f2, a23=w2s*f3;
  float den0=w0s, den1=w1s, den2=w2s;
  for(int c0 = beg; c0 < end; c0 += 64){
    int take = end - c0; if(take > 64) take = 64;
    int idx = esrc[c0 + (lane < take ? lane : take-1)];
    float4 asl = *(const float4*)(als4 + (size_t)idx*4);
    bool act = lane < take;
    float w0l = act ? expc(lrelu(asl.x + adn.x)) : 0.f;
    float w1l = act ? expc(lrelu(asl.y + adn.y)) : 0.f;
    float w2l = act ? expc(lrelu(asl.z + adn.z)) : 0.f;
    int ro = idx << 7;
    int j = 0;
    for(; j+7 < take; j += 8){
      int e0=j+g, e1=j+2+g, e2=j+4+g, e3=j+6+g;
      int r0=__shfl(ro,e0), r1=__shfl(ro,e1), r2=__shfl(ro,e2), r3=__shfl(ro,e3);
      float u00=__shfl(w0l,e0), u01=__shfl(w1l,e0), u02=__shfl(w2l,e0);
      float u10=__shfl(w0l,e1), u11=__shfl(w1l,e1), u12=__shfl(w2l,e1);
      float u20=__shfl(w0l,e2), u21=__shfl(w1l,e2), u22=__shfl(w2l,e2);
      float u30=__shfl(w0l,e3), u31=__shfl(w1l,e3), u32=__shfl(w2l,e3);
      uint2 p0 = *(const uint2*)(hb + r0 + c*4);
      uint2 p1 = *(const uint2*)(hb + r1 + c*4);
      uint2 p2 = *(const uint2*)(hb + r2 + c*4);
      uint2 p3 = *(const uint2*)(hb + r3 + c*4);
      den0 += u00+u10+u20+u30;
      den1 += u01+u11+u21+u31;
      den2 += u02+u12+u22+u32;
      float q00=blo(p0.x), q01=bhi(p0.x), q02=blo(p0.y), q03=bhi(p0.y);
      float q10=blo(p1.x), q11=bhi(p1.x), q12=blo(p1.y), q13=bhi(p1.y);
      float q20=blo(p2.x), q21=bhi(p2.x), q22=blo(p2.y), q23=bhi(p2.y);
      float q30=blo(p3.x), q31=bhi(p3.x), q32=blo(p3.y), q33=bhi(p3.y);
      a00 += u00*q00+u10*q10+u20*q20+u30*q30;
      a01 += u00*q01+u10*q11+u20*q21+u30*q31;
      a02 += u00*q02+u10*q12+u20*q22+u30*q32;
      a03 += u00*q03+u10*q13+u20*q23+u30*q33;
      a10 += u01*q00+u11*q10+u21*q20+u31*q30;
      a11 += u01*q01+u11*q11+u21*q21+u31*q31;
      a12 += u01*q02+u11*q12+u21*q22+u31*q32;
      a13 += u01*q03+u11*q13+u21*q23+u31*q33;
      a20 += u02*q00+u12*q10+u22*q20+u32*q30;
      a21 += u02*q01+u12*q11+u22*q21+u32*q31;
      a22 += u02*q02+u12*q12+u22*q22+u32*q32;
      a23 += u02*q03+u12*q13+u22*q23+u32*q33;
    }
    for(; j < take; j += 2){
      int e = j + g;
      int el = e < 64 ? e : 63;
      int r = __shfl(ro, el);
      float u0 = __shfl(w0l, el), u1 = __shfl(w1l, el), u2 = __shfl(w2l, el);
      if(e >= take){ u0 = 0.f; u1 = 0.f; u2 = 0.f; }
      uint2 p = *(const uint2*)(hb + r + c*4);
      float q0=blo(p.x), q1=bhi(p.x), q2=blo(p.y), q3=bhi(p.y);
      den0 += u0; den1 += u1; den2 += u2;
      a00 += u0*q0; a01 += u0*q1; a02 += u0*q2; a03 += u0*q3;
      a10 += u1*q0; a11 += u1*q1; a12 += u1*q2; a13 += u1*q3;
      a20 += u2*q0; a21 += u2*q1; a22 += u2*q2; a23 += u2*q3;
    }
  }
  a00 += __shfl_xor(a00,32); a01 += __shfl_xor(a01,32); a02 += __shfl_xor(a02,32); a03 += __shfl_xor(a03,32);
  a10 += __shfl_xor(a10,32); a11 += __shfl_xor(a11,32); a12 += __shfl_xor(a12,32); a13 += __shfl_xor(a13,32);
  a20 += __shfl_xor(a20,32); a21 += __shfl_xor(a21,32); a22 += __shfl_xor(a22,32); a23 += __shfl_xor(a23,32);
  den0 += __shfl_xor(den0,32); den1 += __shfl_xor(den1,32); den2 += __shfl_xor(den2,32);
  if(g==0){
    float i0 = 1.f/(3.f*den0), i1 = 1.f/(3.f*den1), i2 = 1.f/(3.f*den2);
    unsigned short* ub = (unsigned short*)U;
    size_t ubase = (size_t)n*384 + c*4;
    uint2 o0, o1, o2;
    o0.x = packbf(a00*i0, a01*i0); o0.y = packbf(a02*i0, a03*i0);
    o1.x = packbf(a10*i1, a11*i1); o1.y = packbf(a12*i1, a13*i1);
    o2.x = packbf(a20*i2, a21*i2); o2.y = packbf(a22*i2, a23*i2);
    *(uint2*)(ub + ubase)       = o0;
    *(uint2*)(ub + ubase + 128) = o1;
    *(uint2*)(ub + ubase + 256) = o2;
  }
}

// pure pool over graphs (h3 already activated); also counts graph sizes per segment
#define NPW_ 16
__global__ __launch_bounds__(256) void k_h3pool(const bf16* __restrict__ H3B,
    const int* __restrict__ batch, float* __restrict__ pooled, float* __restrict__ gcnt){
  int wave = blockIdx.x*4 + (threadIdx.x>>6);
  int lane = threadIdx.x & 63;
  int n0 = wave*NPW_;
  if(n0 >= N_) return;
  int n1 = n0 + NPW_; if(n1 > N_) n1 = N_;
  int f0 = lane*2, f1 = f0+1;
  float r0=0.f, r1=0.f;
  int cur = batch[n0];
  int seg = 0;
  for(int n=n0; n<n1; n++){
    int b = batch[n];
    if(b != cur){
      atomAddF(&pooled[cur*H_ + f0], r0);
      atomAddF(&pooled[cur*H_ + f1], r1);
      if(lane==0) atomAddF(&gcnt[cur], (float)seg);
      r0 = 0.f; r1 = 0.f; seg = 0; cur = b;
    }
    unsigned int hv = *(const unsigned int*)((const unsigned short*)H3B + (size_t)n*H_ + lane*2);
    r0 += blo(hv);
    r1 += bhi(hv);
    seg++;
  }
  atomAddF(&pooled[cur*H_ + f0], r0);
  atomAddF(&pooled[cur*H_ + f1], r1);
  if(lane==0) atomAddF(&gcnt[cur], (float)seg);
}

// per-graph head — fp32 output
__global__ __launch_bounds__(128) void k_head(const float* __restrict__ pooledacc, const float* __restrict__ gcnt,
    const float* __restrict__ protos, const float* __restrict__ Wc, const float* __restrict__ bc,
    const float* __restrict__ Wd1, const float* __restrict__ bd1, const float* __restrict__ Wd2, const float* __restrict__ bd2,
    float* __restrict__ out){
  const int g = blockIdx.x, t = threadIdx.x;
  __shared__ float p[128], xn[128], red[128], sims[32], es[32], asg[32], pe[128], t1[256];
  __shared__ float nrm;
  float cg_ = fmaxf(gcnt[g], 1.f);
  p[t] = pooledacc[g*128 + t] / cg_;
  __syncthreads();
  red[t] = p[t]*p[t];
  __syncthreads();
  for(int s=64;s>0;s>>=1){ if(t<s) red[t]+=red[t+s]; __syncthreads(); }
  if(t==0) nrm = fmaxf(sqrtf(red[0]), 1e-8f);
  __syncthreads();
  xn[t] = p[t]/nrm;
  __syncthreads();
  if(t<32){
    float s=0.f, pn=0.f;
    for(int f=0;f<128;f++){ float pv=protos[t*128+f]; s += xn[f]*pv; pn += pv*pv; }
    sims[t] = s / fmaxf(sqrtf(pn), 1e-8f);
  }
  __syncthreads();
  if(t<32){
    float mx=-1e30f;
    for(int j=0;j<32;j++) mx = fmaxf(mx, sims[j]);
    es[t] = __expf(sims[t]-mx);
  }
  __syncthreads();
  if(t<32){
    float sm=0.f;
    for(int j=0;j<32;j++) sm += es[j];
    float a = es[t]/fmaxf(sm,1e-20f);
    asg[t] = a;
    out[8832 + g*32 + t] = a;
  }
  __syncthreads();
  {
    float s=0.f;
    for(int pp=0;pp<32;pp++) s += asg[pp]*protos[pp*128+t];
    pe[t] = s;
    out[640 + g*128 + t] = s;
  }
  __syncthreads();
  if(t<10){
    float s = bc[t];
    for(int f=0;f<128;f++) s += pe[f]*Wc[f*10+t];
    out[g*10 + t] = s;
  }
  for(int j=t;j<256;j+=128){
    float s = bd1[j];
    for(int f=0;f<128;f++) s += p[f]*Wd1[f*256+j];
    t1[j] = fmaxf(s, 0.f);
  }
  __syncthreads();
  {
    float s = bd2[t];
    for(int j=0;j<256;j++) s += t1[j]*Wd2[j*128+t];
    out[10880 + g*128 + t] = s;
  }
}

__global__ void k_sentinel(float* out, float code){
  out[0] = code;
}

extern "C" void kernel_launch(void* const* d_in, const int* in_sizes, int n_in,
                              void* d_out, int out_size, void* d_ws, size_t ws_size,
                              hipStream_t stream){
  const float* X    = (const float*)d_in[0];
  const int*  EI    = (const int*)d_in[1];
  const int*  batch = (const int*)d_in[2];
  const int* src = EI;
  const int* dst = EI + E_;

  int iW1,ib1,iWl,iWr,ibs,iWg,ias,iad,ibg,ipr,iWc,ibc,iWd1,ibd1,iWd2,ibd2;
  int ig1,ibe1,im1,iv1,ig2,ibe2,im2,iv2,ig3,ibe3,im3,iv3;
  if(n_in >= 31 && in_sizes[5] == 128){
    iW1=3; ib1=4; ig1=5; ibe1=6; im1=7; iv1=8;
    iWl=9; iWr=10; ibs=11; ig2=12; ibe2=13; im2=14; iv2=15;
    iWg=16; ias=17; iad=18; ibg=19; ig3=20; ibe3=21; im3=22; iv3=23;
    ipr=24; iWc=25; ibc=26; iWd1=27; ibd1=28; iWd2=29; ibd2=30;
  }else{
    iW1=3; ib1=4; iWl=5; iWr=6; ibs=7; iWg=8; ias=9; iad=10; ibg=11;
    ipr=12; iWc=13; ibc=14; iWd1=15; ibd1=16; iWd2=17; ibd2=18;
    ig1=19; ibe1=20; im1=21; iv1=22; ig2=23; ibe2=24; im2=25; iv2=26;
    ig3=27; ibe3=28; im3=29; iv3=30;
  }
  const float* W1 = (const float*)d_in[iW1];   const float* b1 = (const float*)d_in[ib1];
  const float* Wl = (const float*)d_in[iWl];   const float* Wr = (const float*)d_in[iWr];
  const float* bs = (const float*)d_in[ibs];   const float* Wg = (const float*)d_in[iWg];
  const float* a_src = (const float*)d_in[ias]; const float* a_dst = (const float*)d_in[iad];
  const float* bg = (const float*)d_in[ibg];   const float* protos = (const float*)d_in[ipr];
  const float* Wc = (const float*)d_in[iWc];   const float* bc = (const float*)d_in[ibc];
  const float* Wd1 = (const float*)d_in[iWd1]; const float* bd1 = (const float*)d_in[ibd1];
  const float* Wd2 = (const float*)d_in[iWd2]; const float* bd2 = (const float*)d_in[ibd2];
  const float* g1 = (const float*)d_in[ig1];   const float* be1 = (const float*)d_in[ibe1];
  const float* m1 = (const float*)d_in[im1];   const float* v1 = (const float*)d_in[iv1];
  const float* g2 = (const float*)d_in[ig2];   const float* be2 = (const float*)d_in[ibe2];
  const float* m2 = (const float*)d_in[im2];   const float* v2 = (const float*)d_in[iv2];
  const float* g3 = (const float*)d_in[ig3];   const float* be3 = (const float*)d_in[ibe3];
  const float* m3 = (const float*)d_in[im3];   const float* v3 = (const float*)d_in[iv3];

  const size_t NF = (size_t)N_*H_;
  // ints: cnt(N) + row_ptr(N+4) + tmp(N) + esrc(E) + bsum(64) + boff(64)
  const size_t intN = (size_t)3*N_ + 4 + (size_t)E_ + 128;
  // floats: dinv(N) + als4(4N) + ald4(4N) + pooled(G*H) + gcnt(G) + vs3(384) + vd3(384)
  const size_t fltN = (size_t)9*N_ + G_*H_ + G_ + 768;
  const size_t NEED = NF*2*3 + (size_t)N_*384*2 + intN*4 + fltN*4 + (size_t)6*16384*2;
  if(ws_size < NEED){
    k_sentinel<<<1,1,0,stream>>>((float*)d_out, 1000.f + (float)(ws_size>>20));
    return;
  }
  bf16* RA = (bf16*)d_ws;            // h -> h2
  bf16* RB = RA + NF;                // h1
  bf16* RC = RB + NF;                // mean_nb -> h3
  bf16* U  = RC + NF;                // N x 384 aggregated h2-space (3 heads)
  int*  cnt     = (int*)(U + (size_t)N_*384);
  int*  row_ptr = cnt + N_;
  int*  tmp     = row_ptr + (N_+4);
  int*  esrc    = tmp + N_;
  int*  bsum    = esrc + E_;
  int*  boff    = bsum + 64;
  float* dinv   = (float*)(boff + 64);
  float* als4   = dinv + N_;         // N*4 (16B-aligned)
  float* ald4   = als4 + (size_t)N_*4;
  float* pooled = ald4 + (size_t)N_*4;
  float* gcnt   = pooled + (size_t)G_*H_;
  float* vs3    = gcnt + G_;
  float* vd3    = vs3 + 384;
  unsigned short* WTg = (unsigned short*)(vd3 + 384);

  // ---- weight prep + CSR build ----
  k_wprep<<<(6*16384+255)/256, 256, 0, stream>>>(W1, Wl, Wr, Wg, WTg);
  k_vprep<<<1, 384, 0, stream>>>(Wg, a_src, a_dst, vs3, vd3);
  hipMemsetAsync(cnt, 0, N_*sizeof(int), stream);
  hipMemsetAsync(pooled, 0, (size_t)(G_*H_+G_)*sizeof(float), stream);
  k_count<<<(E_+255)/256, 256, 0, stream>>>(dst, cnt);
  k_scan1<<<NB_, 1024, 0, stream>>>(cnt, row_ptr, dinv, bsum);
  k_scan2<<<1, 64, 0, stream>>>(bsum, boff, row_ptr);
  k_scan3<<<(N_+255)/256, 256, 0, stream>>>(row_ptr, boff, tmp);
  k_scatter<<<(E_+255)/256, 256, 0, stream>>>(src, dst, tmp, esrc);

  const int GB = (N_+3)/4;
  const int MB = (N_+63)/64;
  // ---- GCN ----
  k_mm_x<<<MB, 256, 0, stream>>>(X, WTg, RA);
  k_gcn_gather<<<GB, 256, 0, stream>>>(row_ptr, esrc, dinv, RA, b1, g1, be1, m1, v1, RB);
  // ---- SAGE (+ fused GAT logits) ----
  k_sage_gather<<<GB, 256, 0, stream>>>(row_ptr, esrc, RB, RC);
  k_sage_mm_att<<<MB, 256, 0, stream>>>(RC, RB, WTg + 16384, WTg + 2*16384, bs, g2, be2, m2, v2,
                                        vs3, vd3, RA, als4, ald4);
  // ---- GAT: h2-space aggregation (edge weights fused), then one K=384 GEMM ----
  k_gat_agg<<<GB, 256, 0, stream>>>(row_ptr, esrc, als4, ald4, RA, U);
  k_gat_mm3<<<MB, 256, 0, stream>>>(U, WTg + 3*16384, bg, g3, be3, m3, v3, RC);
  // ---- pool + head ----
  {
    int waves = (N_ + NPW_ - 1)/NPW_;
    int blocks = (waves + 3)/4;
    k_h3pool<<<blocks, 256, 0, stream>>>(RC, batch, pooled, gcnt);
  }
  k_head<<<G_, 128, 0, stream>>>(pooled, gcnt, protos, Wc, bc, Wd1, bd1, Wd2, bd2, (float*)d_out);
}

// Round 10
// 397.668 us; speedup vs baseline: 1.0676x; 1.0378x over previous
//
#include <hip/hip_runtime.h>
#include <hip/hip_bf16.h>
#include <stdint.h>
#include <stddef.h>

#define N_ 50000
#define E_ 600000
#define F_ 128
#define H_ 128
#define G_ 64
#define P_ 32
#define C_ 10
#define NB_ 49   // scan blocks: ceil(N/1024)

typedef __hip_bfloat16 bf16;
typedef __attribute__((ext_vector_type(8))) short short8;
typedef __attribute__((ext_vector_type(4))) float float4v;

__device__ __forceinline__ unsigned short f2us(float x){ bf16 h = __float2bfloat16(x); return *(unsigned short*)&h; }
__device__ __forceinline__ float blo(unsigned int u){ return __uint_as_float(u<<16); }
__device__ __forceinline__ float bhi(unsigned int u){ return __uint_as_float(u & 0xFFFF0000u); }
__device__ __forceinline__ unsigned int packbf(float lo, float hi){ return ((unsigned int)f2us(hi)<<16) | f2us(lo); }
__device__ __forceinline__ float eluf(float x){ return x>0.f ? x : __expf(x)-1.f; }
__device__ __forceinline__ float bnf(float x,float m,float v,float g,float b){ return (x-m)*rsqrtf(v+1e-5f)*g+b; }
__device__ __forceinline__ float lrelu(float x){ return x>0.f ? x : 0.2f*x; }
__device__ __forceinline__ float expc(float x){ return __expf(fminf(x, 50.f)); }
__device__ __forceinline__ void atomAddF(float* a, float v){ unsafeAtomicAdd(a, v); }

// ---------------- weight prep: per-lane MFMA B-fragment layout ----------------
__global__ __launch_bounds__(256) void k_wprep(const float* __restrict__ W1, const float* __restrict__ Wl,
    const float* __restrict__ Wr, const float* __restrict__ Wg, unsigned short* __restrict__ WT){
  int idx = blockIdx.x*256 + threadIdx.x;
  if(idx >= 6*16384) return;
  int m    = idx >> 14;
  int tile = (idx >> 11) & 7;
  int kc   = (idx >> 9) & 3;
  int lane = (idx >> 3) & 63;
  int j    = idx & 7;
  int k = kc*32 + (lane>>4)*8 + j;
  int n = tile*16 + (lane&15);
  float v;
  if(m==0)      v = W1[k*128+n];
  else if(m==1) v = Wl[k*128+n];
  else if(m==2) v = Wr[k*128+n];
  else          v = Wg[k*384 + (m-3)*128 + n];
  WT[idx] = f2us(v);
}

// vs3[h*128+f] = sum_j Wg[f, h*128+j] * a_src[h,j]  (and vd3 with a_dst)
__global__ __launch_bounds__(384) void k_vprep(const float* __restrict__ Wg, const float* __restrict__ a_src,
    const float* __restrict__ a_dst, float* __restrict__ vs3, float* __restrict__ vd3){
  int t = threadIdx.x;
  if(t >= 384) return;
  int h = t >> 7, f = t & 127;
  const float4* wr = (const float4*)(Wg + (size_t)f*384 + h*128);
  const float4* as = (const float4*)(a_src + h*128);
  const float4* ad = (const float4*)(a_dst + h*128);
  float s = 0.f, d = 0.f;
  #pragma unroll 8
  for(int j=0;j<32;j++){
    float4 wv = wr[j], av = as[j], dv = ad[j];
    s += wv.x*av.x + wv.y*av.y + wv.z*av.z + wv.w*av.w;
    d += wv.x*dv.x + wv.y*dv.y + wv.z*dv.z + wv.w*dv.w;
  }
  vs3[t] = s; vd3[t] = d;
}

// ---------------- MFMA GEMM helpers (LDS-free, sync-free) ----------------
__device__ __forceinline__ void load_Afrag_bf16(const bf16* A, int row, int lane, short8 af[4]){
  const unsigned short* ap = (const unsigned short*)A + (size_t)row*128 + (lane>>4)*8;
  #pragma unroll
  for(int kc=0;kc<4;kc++) af[kc] = *(const short8*)(ap + kc*32);
}
__device__ __forceinline__ void mfma_pass_g(const unsigned short* __restrict__ WB, const short8 af[4],
                                            int lane, float4v acc[8]){
  #pragma unroll
  for(int tile=0;tile<8;tile++){
    #pragma unroll
    for(int kc=0;kc<4;kc++){
      short8 bfv = *(const short8*)(WB + (((tile*4+kc)*64 + lane)<<3));
      acc[tile] = __builtin_amdgcn_mfma_f32_16x16x32_bf16(af[kc], bfv, acc[tile], 0, 0, 0);
    }
  }
}

// h(bf16) = X(f32) @ W1
__global__ __launch_bounds__(256) void k_mm_x(const float* __restrict__ X, const unsigned short* __restrict__ WTg,
                                              bf16* __restrict__ HB){
  const int tid = threadIdx.x, lane = tid&63, w = tid>>6;
  const int row0 = blockIdx.x*64;
  int arow = row0 + w*16 + (lane&15);
  int ar = arow < N_ ? arow : N_-1;
  const float* ap = X + (size_t)ar*128 + (lane>>4)*8;
  short8 af[4];
  #pragma unroll
  for(int kc=0;kc<4;kc++){
    float4 a = *(const float4*)(ap + kc*32);
    float4 b = *(const float4*)(ap + kc*32 + 4);
    short8 v;
    v[0]=(short)f2us(a.x); v[1]=(short)f2us(a.y); v[2]=(short)f2us(a.z); v[3]=(short)f2us(a.w);
    v[4]=(short)f2us(b.x); v[5]=(short)f2us(b.y); v[6]=(short)f2us(b.z); v[7]=(short)f2us(b.w);
    af[kc]=v;
  }
  float4v acc[8];
  #pragma unroll
  for(int t=0;t<8;t++){ acc[t][0]=0.f; acc[t][1]=0.f; acc[t][2]=0.f; acc[t][3]=0.f; }
  mfma_pass_g(WTg, af, lane, acc);
  const int colb = lane&15, q = lane>>4;
  unsigned short* ob = (unsigned short*)HB;
  #pragma unroll
  for(int r=0;r<4;r++){
    int ro = row0 + w*16 + q*4 + r;
    if(ro < N_){
      #pragma unroll
      for(int tile=0;tile<8;tile++)
        ob[(size_t)ro*128 + tile*16 + colb] = f2us(acc[tile][r]);
    }
  }
}

// h2(bf16) = elu(bn2( mean@Wl + h1@Wr + bs )) ; fused GAT logits als4/ald4 = h2 . vs/vd
__global__ __launch_bounds__(256) void k_sage_mm_att(const bf16* __restrict__ MaB, const bf16* __restrict__ H1B,
    const unsigned short* __restrict__ WlF, const unsigned short* __restrict__ WrF,
    const float* __restrict__ bs, const float* __restrict__ g2, const float* __restrict__ be2,
    const float* __restrict__ m2, const float* __restrict__ v2,
    const float* __restrict__ vs3, const float* __restrict__ vd3,
    bf16* __restrict__ H2B, float* __restrict__ als4, float* __restrict__ ald4){
  const int tid = threadIdx.x, lane = tid&63, w = tid>>6;
  const int row0 = blockIdx.x*64;
  int arow = row0 + w*16 + (lane&15);
  int ar = arow < N_ ? arow : N_-1;
  float4v acc[8];
  #pragma unroll
  for(int t=0;t<8;t++){ acc[t][0]=0.f; acc[t][1]=0.f; acc[t][2]=0.f; acc[t][3]=0.f; }
  short8 af[4];
  load_Afrag_bf16(MaB, ar, lane, af);
  mfma_pass_g(WlF, af, lane, acc);
  load_Afrag_bf16(H1B, ar, lane, af);
  mfma_pass_g(WrF, af, lane, acc);

  const int colb = lane&15, q = lane>>4;
  float vsv[24], vdv[24];
  #pragma unroll
  for(int h=0;h<3;h++){
    #pragma unroll
    for(int tile=0;tile<8;tile++){
      vsv[h*8+tile] = vs3[h*128 + tile*16 + colb];
      vdv[h*8+tile] = vd3[h*128 + tile*16 + colb];
    }
  }
  unsigned short* ob = (unsigned short*)H2B;
  #pragma unroll
  for(int tile=0;tile<8;tile++){
    int col = tile*16 + colb;
    float bsv=bs[col], gv=g2[col], bev=be2[col], mv=m2[col], vv=v2[col];
    #pragma unroll
    for(int r=0;r<4;r++){
      int ro = row0 + w*16 + q*4 + r;
      float x = eluf(bnf(acc[tile][r] + bsv, mv, vv, gv, bev));
      acc[tile][r] = x;
      if(ro < N_) ob[(size_t)ro*128 + col] = f2us(x);
    }
  }
  #pragma unroll
  for(int r=0;r<4;r++){
    int ro = row0 + w*16 + q*4 + r;
    #pragma unroll
    for(int h=0;h<3;h++){
      float ps=0.f, pd=0.f;
      #pragma unroll
      for(int tile=0;tile<8;tile++){ ps += acc[tile][r]*vsv[h*8+tile]; pd += acc[tile][r]*vdv[h*8+tile]; }
      #pragma unroll
      for(int o=8;o>0;o>>=1){ ps += __shfl_down(ps,o,16); pd += __shfl_down(pd,o,16); }
      if(colb==0 && ro<N_){ als4[ro*4+h] = ps; ald4[ro*4+h] = pd; }
    }
  }
}

// h3(bf16) = elu(bn3( sum_h U_h @ Wg_h + bg ))  where U = [U0|U1|U2] is N x 384
__global__ __launch_bounds__(256) void k_gat_mm3(const bf16* __restrict__ U, const unsigned short* __restrict__ WgF,
    const float* __restrict__ bg, const float* __restrict__ g3, const float* __restrict__ be3,
    const float* __restrict__ m3, const float* __restrict__ v3, bf16* __restrict__ H3B){
  const int tid = threadIdx.x, lane = tid&63, w = tid>>6;
  const int row0 = blockIdx.x*64;
  int arow = row0 + w*16 + (lane&15);
  int ar = arow < N_ ? arow : N_-1;
  float4v acc[8];
  #pragma unroll
  for(int t=0;t<8;t++){ acc[t][0]=0.f; acc[t][1]=0.f; acc[t][2]=0.f; acc[t][3]=0.f; }
  short8 af[4];
  for(int hh=0; hh<3; hh++){
    const unsigned short* ap = (const unsigned short*)U + (size_t)ar*384 + hh*128 + (lane>>4)*8;
    #pragma unroll
    for(int kc=0;kc<4;kc++) af[kc] = *(const short8*)(ap + kc*32);
    mfma_pass_g(WgF + hh*16384, af, lane, acc);
  }
  const int colb = lane&15, q = lane>>4;
  unsigned short* ob = (unsigned short*)H3B;
  #pragma unroll
  for(int tile=0;tile<8;tile++){
    int col = tile*16 + colb;
    float bgv=bg[col], gv=g3[col], bev=be3[col], mv=m3[col], vv=v3[col];
    #pragma unroll
    for(int r=0;r<4;r++){
      int ro = row0 + w*16 + q*4 + r;
      if(ro < N_){
        float x = acc[tile][r] + bgv;
        ob[(size_t)ro*128 + col] = f2us(eluf(bnf(x, mv, vv, gv, bev)));
      }
    }
  }
}

// ---------------- CSR build ----------------
__global__ __launch_bounds__(256) void k_count(const int* __restrict__ dst, int* __restrict__ cnt){
  int e = blockIdx.x*256 + threadIdx.x;
  if(e < E_) atomicAdd(&cnt[dst[e]], 1);
}

__global__ __launch_bounds__(1024) void k_scan1(const int* __restrict__ cnt, int* __restrict__ row_ptr,
                                                float* __restrict__ dinv, int* __restrict__ bsum){
  __shared__ int wsum[16];
  const int t = threadIdx.x, lane = t & 63, wid = t >> 6;
  int i = blockIdx.x*1024 + t;
  int v = (i<N_) ? cnt[i] : 0;
  int x = v;
  #pragma unroll
  for(int o=1;o<64;o<<=1){
    int y = __shfl_up(x, o, 64);
    if(lane >= o) x += y;
  }
  if(lane==63) wsum[wid] = x;
  __syncthreads();
  if(wid==0){
    int s = (lane<16) ? wsum[lane] : 0;
    #pragma unroll
    for(int o=1;o<16;o<<=1){
      int y = __shfl_up(s, o, 64);
      if(lane >= o) s += y;
    }
    if(lane<16) wsum[lane] = s;
  }
  __syncthreads();
  int waveoff = (wid>0) ? wsum[wid-1] : 0;
  int incl = waveoff + x;
  if(i<N_){
    row_ptr[i] = incl - v;
    dinv[i] = rsqrtf((float)v + 1.f);
  }
  if(t==1023) bsum[blockIdx.x] = incl;
}

__global__ __launch_bounds__(64) void k_scan2(const int* __restrict__ bsum, int* __restrict__ boff,
                                              int* __restrict__ row_ptr){
  int lane = threadIdx.x;
  int v = (lane < NB_) ? bsum[lane] : 0;
  int x = v;
  #pragma unroll
  for(int o=1;o<64;o<<=1){
    int y = __shfl_up(x, o, 64);
    if(lane >= o) x += y;
  }
  if(lane < NB_) boff[lane] = x - v;
  if(lane == 63) row_ptr[N_] = x;
}

__global__ __launch_bounds__(256) void k_scan3(int* __restrict__ row_ptr, const int* __restrict__ boff,
                                               int* __restrict__ tmp){
  int i = blockIdx.x*256 + threadIdx.x;
  if(i < N_){
    int r = row_ptr[i] + boff[i>>10];
    row_ptr[i] = r;
    tmp[i] = r;
  }
}

__global__ __launch_bounds__(256) void k_scatter(const int* __restrict__ src, const int* __restrict__ dst,
                                                 int* __restrict__ tmp, int* __restrict__ esrc){
  int e = blockIdx.x*256 + threadIdx.x;
  if(e < E_){
    int d = dst[e];
    int pos = atomicAdd(&tmp[d], 1);
    esrc[pos] = src[e];
  }
}

// ---------------- CSR gather kernels: 1 node per 64-thread block ----
// Split-wave: g = lane>>5 picks which of 2 edges; c = lane&31 covers 4 bf16 features at
// element offset c*4 (8B). 32 lanes x 8B = one 256B row per group; 2 rows per wave-load.
// Stage idx<<7 + per-edge weights once per 64 edges; cross-group combine via shfl_xor(32).

__global__ __launch_bounds__(64) void k_gcn_gather(const int* __restrict__ row_ptr, const int* __restrict__ esrc,
    const float* __restrict__ dinv, const bf16* __restrict__ HB,
    const float* __restrict__ b1, const float* __restrict__ g1, const float* __restrict__ be1,
    const float* __restrict__ m1, const float* __restrict__ v1, bf16* __restrict__ H1B){
  int n = blockIdx.x;
  int lane = threadIdx.x & 63;
  const int g = lane>>5, c = lane&31;
  int beg = row_ptr[n], end = row_ptr[n+1];
  float dn = dinv[n];
  const unsigned short* hb = (const unsigned short*)HB;
  uint2 ps = *(const uint2*)(hb + (size_t)n*H_ + c*4);
  float ws = (g==0) ? dn*dn : 0.f;
  float a0 = ws*blo(ps.x), a1 = ws*bhi(ps.x), a2 = ws*blo(ps.y), a3 = ws*bhi(ps.y);
  for(int c0 = beg; c0 < end; c0 += 64){
    int take = end - c0; if(take > 64) take = 64;
    int idx = esrc[c0 + (lane < take ? lane : take-1)];
    float wl = (lane < take) ? dinv[idx]*dn : 0.f;
    int ro = idx << 7;
    int j = 0;
    for(; j+7 < take; j += 8){
      int e0=j+g, e1=j+2+g, e2=j+4+g, e3=j+6+g;
      int r0=__shfl(ro,e0), r1=__shfl(ro,e1), r2=__shfl(ro,e2), r3=__shfl(ro,e3);
      float u0=__shfl(wl,e0), u1=__shfl(wl,e1), u2=__shfl(wl,e2), u3=__shfl(wl,e3);
      uint2 p0 = *(const uint2*)(hb + r0 + c*4);
      uint2 p1 = *(const uint2*)(hb + r1 + c*4);
      uint2 p2 = *(const uint2*)(hb + r2 + c*4);
      uint2 p3 = *(const uint2*)(hb + r3 + c*4);
      a0 += u0*blo(p0.x)+u1*blo(p1.x)+u2*blo(p2.x)+u3*blo(p3.x);
      a1 += u0*bhi(p0.x)+u1*bhi(p1.x)+u2*bhi(p2.x)+u3*bhi(p3.x);
      a2 += u0*blo(p0.y)+u1*blo(p1.y)+u2*blo(p2.y)+u3*blo(p3.y);
      a3 += u0*bhi(p0.y)+u1*bhi(p1.y)+u2*bhi(p2.y)+u3*bhi(p3.y);
    }
    for(; j < take; j += 2){
      int e = j + g;
      int el = e < 64 ? e : 63;
      int r = __shfl(ro, el);
      float u = __shfl(wl, el);
      if(e >= take) u = 0.f;
      uint2 p = *(const uint2*)(hb + r + c*4);
      a0 += u*blo(p.x); a1 += u*bhi(p.x); a2 += u*blo(p.y); a3 += u*bhi(p.y);
    }
  }
  a0 += __shfl_xor(a0,32); a1 += __shfl_xor(a1,32);
  a2 += __shfl_xor(a2,32); a3 += __shfl_xor(a3,32);
  if(g==0){
    float4 bv = *(const float4*)(b1 + c*4);
    float4 mv = *(const float4*)(m1 + c*4);
    float4 vv = *(const float4*)(v1 + c*4);
    float4 gv = *(const float4*)(g1 + c*4);
    float4 ev = *(const float4*)(be1 + c*4);
    uint2 o;
    o.x = packbf(eluf(bnf(a0+bv.x, mv.x, vv.x, gv.x, ev.x)),
                 eluf(bnf(a1+bv.y, mv.y, vv.y, gv.y, ev.y)));
    o.y = packbf(eluf(bnf(a2+bv.z, mv.z, vv.z, gv.z, ev.z)),
                 eluf(bnf(a3+bv.w, mv.w, vv.w, gv.w, ev.w)));
    *(uint2*)((unsigned short*)H1B + (size_t)n*H_ + c*4) = o;
  }
}

__global__ __launch_bounds__(64) void k_sage_gather(const int* __restrict__ row_ptr, const int* __restrict__ esrc,
    const bf16* __restrict__ H1B, bf16* __restrict__ MeanB){
  int n = blockIdx.x;
  int lane = threadIdx.x & 63;
  const int g = lane>>5, c = lane&31;
  int beg = row_ptr[n], end = row_ptr[n+1];
  const unsigned short* hb = (const unsigned short*)H1B;
  float a0=0.f, a1=0.f, a2=0.f, a3=0.f;
  for(int c0 = beg; c0 < end; c0 += 64){
    int take = end - c0; if(take > 64) take = 64;
    int idx = esrc[c0 + (lane < take ? lane : take-1)];
    float wl = (lane < take) ? 1.f : 0.f;
    int ro = idx << 7;
    int j = 0;
    for(; j+7 < take; j += 8){
      int e0=j+g, e1=j+2+g, e2=j+4+g, e3=j+6+g;
      int r0=__shfl(ro,e0), r1=__shfl(ro,e1), r2=__shfl(ro,e2), r3=__shfl(ro,e3);
      float u0=__shfl(wl,e0), u1=__shfl(wl,e1), u2=__shfl(wl,e2), u3=__shfl(wl,e3);
      uint2 p0 = *(const uint2*)(hb + r0 + c*4);
      uint2 p1 = *(const uint2*)(hb + r1 + c*4);
      uint2 p2 = *(const uint2*)(hb + r2 + c*4);
      uint2 p3 = *(const uint2*)(hb + r3 + c*4);
      a0 += u0*blo(p0.x)+u1*blo(p1.x)+u2*blo(p2.x)+u3*blo(p3.x);
      a1 += u0*bhi(p0.x)+u1*bhi(p1.x)+u2*bhi(p2.x)+u3*bhi(p3.x);
      a2 += u0*blo(p0.y)+u1*blo(p1.y)+u2*blo(p2.y)+u3*blo(p3.y);
      a3 += u0*bhi(p0.y)+u1*bhi(p1.y)+u2*bhi(p2.y)+u3*bhi(p3.y);
    }
    for(; j < take; j += 2){
      int e = j + g;
      int el = e < 64 ? e : 63;
      int r = __shfl(ro, el);
      float u = __shfl(wl, el);
      if(e >= take) u = 0.f;
      uint2 p = *(const uint2*)(hb + r + c*4);
      a0 += u*blo(p.x); a1 += u*bhi(p.x); a2 += u*blo(p.y); a3 += u*bhi(p.y);
    }
  }
  a0 += __shfl_xor(a0,32); a1 += __shfl_xor(a1,32);
  a2 += __shfl_xor(a2,32); a3 += __shfl_xor(a3,32);
  if(g==0){
    float inv = 1.f / fmaxf((float)(end-beg), 1.f);
    uint2 o;
    o.x = packbf(a0*inv, a1*inv);
    o.y = packbf(a2*inv, a3*inv);
    *(uint2*)((unsigned short*)MeanB + (size_t)n*H_ + c*4) = o;
  }
}

// GAT aggregation in h2-space, fused edge weights, split-wave inner loop.
__global__ __launch_bounds__(64) void k_gat_agg(const int* __restrict__ row_ptr, const int* __restrict__ esrc,
    const float* __restrict__ als4, const float* __restrict__ ald4,
    const bf16* __restrict__ H2B, bf16* __restrict__ U){
  int n = blockIdx.x;
  int lane = threadIdx.x & 63;
  const int g = lane>>5, c = lane&31;
  int beg = row_ptr[n], end = row_ptr[n+1];
  float4 asn = *(const float4*)(als4 + (size_t)n*4);
  float4 adn = *(const float4*)(ald4 + (size_t)n*4);
  float es0 = expc(lrelu(asn.x + adn.x));
  float es1 = expc(lrelu(asn.y + adn.y));
  float es2 = expc(lrelu(asn.z + adn.z));
  const unsigned short* hb = (const unsigned short*)H2B;
  uint2 ps = *(const uint2*)(hb + (size_t)n*H_ + c*4);
  float w0s = (g==0) ? es0 : 0.f;
  float w1s = (g==0) ? es1 : 0.f;
  float w2s = (g==0) ? es2 : 0.f;
  float f0=blo(ps.x), f1=bhi(ps.x), f2=blo(ps.y), f3=bhi(ps.y);
  float a00=w0s*f0, a01=w0s*f1, a02=w0s*f2, a03=w0s*f3;
  float a10=w1s*f0, a11=w1s*f1, a12=w1s*f2, a13=w1s*f3;
  float a20=w2s*f0, a21=w2s*f1, a22=w2s*f2, a23=w2s*f3;
  float den0=w0s, den1=w1s, den2=w2s;
  for(int c0 = beg; c0 < end; c0 += 64){
    int take = end - c0; if(take > 64) take = 64;
    int idx = esrc[c0 + (lane < take ? lane : take-1)];
    float4 asl = *(const float4*)(als4 + (size_t)idx*4);
    bool act = lane < take;
    float w0l = act ? expc(lrelu(asl.x + adn.x)) : 0.f;
    float w1l = act ? expc(lrelu(asl.y + adn.y)) : 0.f;
    float w2l = act ? expc(lrelu(asl.z + adn.z)) : 0.f;
    int ro = idx << 7;
    int j = 0;
    for(; j+7 < take; j += 8){
      int e0=j+g, e1=j+2+g, e2=j+4+g, e3=j+6+g;
      int r0=__shfl(ro,e0), r1=__shfl(ro,e1), r2=__shfl(ro,e2), r3=__shfl(ro,e3);
      float u00=__shfl(w0l,e0), u01=__shfl(w1l,e0), u02=__shfl(w2l,e0);
      float u10=__shfl(w0l,e1), u11=__shfl(w1l,e1), u12=__shfl(w2l,e1);
      float u20=__shfl(w0l,e2), u21=__shfl(w1l,e2), u22=__shfl(w2l,e2);
      float u30=__shfl(w0l,e3), u31=__shfl(w1l,e3), u32=__shfl(w2l,e3);
      uint2 p0 = *(const uint2*)(hb + r0 + c*4);
      uint2 p1 = *(const uint2*)(hb + r1 + c*4);
      uint2 p2 = *(const uint2*)(hb + r2 + c*4);
      uint2 p3 = *(const uint2*)(hb + r3 + c*4);
      den0 += u00+u10+u20+u30;
      den1 += u01+u11+u21+u31;
      den2 += u02+u12+u22+u32;
      float q00=blo(p0.x), q01=bhi(p0.x), q02=blo(p0.y), q03=bhi(p0.y);
      float q10=blo(p1.x), q11=bhi(p1.x), q12=blo(p1.y), q13=bhi(p1.y);
      float q20=blo(p2.x), q21=bhi(p2.x), q22=blo(p2.y), q23=bhi(p2.y);
      float q30=blo(p3.x), q31=bhi(p3.x), q32=blo(p3.y), q33=bhi(p3.y);
      a00 += u00*q00+u10*q10+u20*q20+u30*q30;
      a01 += u00*q01+u10*q11+u20*q21+u30*q31;
      a02 += u00*q02+u10*q12+u20*q22+u30*q32;
      a03 += u00*q03+u10*q13+u20*q23+u30*q33;
      a10 += u01*q00+u11*q10+u21*q20+u31*q30;
      a11 += u01*q01+u11*q11+u21*q21+u31*q31;
      a12 += u01*q02+u11*q12+u21*q22+u31*q32;
      a13 += u01*q03+u11*q13+u21*q23+u31*q33;
      a20 += u02*q00+u12*q10+u22*q20+u32*q30;
      a21 += u02*q01+u12*q11+u22*q21+u32*q31;
      a22 += u02*q02+u12*q12+u22*q22+u32*q32;
      a23 += u02*q03+u12*q13+u22*q23+u32*q33;
    }
    for(; j < take; j += 2){
      int e = j + g;
      int el = e < 64 ? e : 63;
      int r = __shfl(ro, el);
      float u0 = __shfl(w0l, el), u1 = __shfl(w1l, el), u2 = __shfl(w2l, el);
      if(e >= take){ u0 = 0.f; u1 = 0.f; u2 = 0.f; }
      uint2 p = *(const uint2*)(hb + r + c*4);
      float q0=blo(p.x), q1=bhi(p.x), q2=blo(p.y), q3=bhi(p.y);
      den0 += u0; den1 += u1; den2 += u2;
      a00 += u0*q0; a01 += u0*q1; a02 += u0*q2; a03 += u0*q3;
      a10 += u1*q0; a11 += u1*q1; a12 += u1*q2; a13 += u1*q3;
      a20 += u2*q0; a21 += u2*q1; a22 += u2*q2; a23 += u2*q3;
    }
  }
  a00 += __shfl_xor(a00,32); a01 += __shfl_xor(a01,32); a02 += __shfl_xor(a02,32); a03 += __shfl_xor(a03,32);
  a10 += __shfl_xor(a10,32); a11 += __shfl_xor(a11,32); a12 += __shfl_xor(a12,32); a13 += __shfl_xor(a13,32);
  a20 += __shfl_xor(a20,32); a21 += __shfl_xor(a21,32); a22 += __shfl_xor(a22,32); a23 += __shfl_xor(a23,32);
  den0 += __shfl_xor(den0,32); den1 += __shfl_xor(den1,32); den2 += __shfl_xor(den2,32);
  if(g==0){
    float i0 = 1.f/(3.f*den0), i1 = 1.f/(3.f*den1), i2 = 1.f/(3.f*den2);
    unsigned short* ub = (unsigned short*)U;
    size_t ubase = (size_t)n*384 + c*4;
    uint2 o0, o1, o2;
    o0.x = packbf(a00*i0, a01*i0); o0.y = packbf(a02*i0, a03*i0);
    o1.x = packbf(a10*i1, a11*i1); o1.y = packbf(a12*i1, a13*i1);
    o2.x = packbf(a20*i2, a21*i2); o2.y = packbf(a22*i2, a23*i2);
    *(uint2*)(ub + ubase)       = o0;
    *(uint2*)(ub + ubase + 128) = o1;
    *(uint2*)(ub + ubase + 256) = o2;
  }
}

// pure pool over graphs (h3 already activated); also counts graph sizes per segment
#define NPW_ 16
__global__ __launch_bounds__(256) void k_h3pool(const bf16* __restrict__ H3B,
    const int* __restrict__ batch, float* __restrict__ pooled, float* __restrict__ gcnt){
  int wave = blockIdx.x*4 + (threadIdx.x>>6);
  int lane = threadIdx.x & 63;
  int n0 = wave*NPW_;
  if(n0 >= N_) return;
  int n1 = n0 + NPW_; if(n1 > N_) n1 = N_;
  int f0 = lane*2, f1 = f0+1;
  float r0=0.f, r1=0.f;
  int cur = batch[n0];
  int seg = 0;
  for(int n=n0; n<n1; n++){
    int b = batch[n];
    if(b != cur){
      atomAddF(&pooled[cur*H_ + f0], r0);
      atomAddF(&pooled[cur*H_ + f1], r1);
      if(lane==0) atomAddF(&gcnt[cur], (float)seg);
      r0 = 0.f; r1 = 0.f; seg = 0; cur = b;
    }
    unsigned int hv = *(const unsigned int*)((const unsigned short*)H3B + (size_t)n*H_ + lane*2);
    r0 += blo(hv);
    r1 += bhi(hv);
    seg++;
  }
  atomAddF(&pooled[cur*H_ + f0], r0);
  atomAddF(&pooled[cur*H_ + f1], r1);
  if(lane==0) atomAddF(&gcnt[cur], (float)seg);
}

// per-graph head — fp32 output
__global__ __launch_bounds__(128) void k_head(const float* __restrict__ pooledacc, const float* __restrict__ gcnt,
    const float* __restrict__ protos, const float* __restrict__ Wc, const float* __restrict__ bc,
    const float* __restrict__ Wd1, const float* __restrict__ bd1, const float* __restrict__ Wd2, const float* __restrict__ bd2,
    float* __restrict__ out){
  const int g = blockIdx.x, t = threadIdx.x;
  __shared__ float p[128], xn[128], red[128], sims[32], es[32], asg[32], pe[128], t1[256];
  __shared__ float nrm;
  float cg_ = fmaxf(gcnt[g], 1.f);
  p[t] = pooledacc[g*128 + t] / cg_;
  __syncthreads();
  red[t] = p[t]*p[t];
  __syncthreads();
  for(int s=64;s>0;s>>=1){ if(t<s) red[t]+=red[t+s]; __syncthreads(); }
  if(t==0) nrm = fmaxf(sqrtf(red[0]), 1e-8f);
  __syncthreads();
  xn[t] = p[t]/nrm;
  __syncthreads();
  if(t<32){
    float s=0.f, pn=0.f;
    for(int f=0;f<128;f++){ float pv=protos[t*128+f]; s += xn[f]*pv; pn += pv*pv; }
    sims[t] = s / fmaxf(sqrtf(pn), 1e-8f);
  }
  __syncthreads();
  if(t<32){
    float mx=-1e30f;
    for(int j=0;j<32;j++) mx = fmaxf(mx, sims[j]);
    es[t] = __expf(sims[t]-mx);
  }
  __syncthreads();
  if(t<32){
    float sm=0.f;
    for(int j=0;j<32;j++) sm += es[j];
    float a = es[t]/fmaxf(sm,1e-20f);
    asg[t] = a;
    out[8832 + g*32 + t] = a;
  }
  __syncthreads();
  {
    float s=0.f;
    for(int pp=0;pp<32;pp++) s += asg[pp]*protos[pp*128+t];
    pe[t] = s;
    out[640 + g*128 + t] = s;
  }
  __syncthreads();
  if(t<10){
    float s = bc[t];
    for(int f=0;f<128;f++) s += pe[f]*Wc[f*10+t];
    out[g*10 + t] = s;
  }
  for(int j=t;j<256;j+=128){
    float s = bd1[j];
    for(int f=0;f<128;f++) s += p[f]*Wd1[f*256+j];
    t1[j] = fmaxf(s, 0.f);
  }
  __syncthreads();
  {
    float s = bd2[t];
    for(int j=0;j<256;j++) s += t1[j]*Wd2[j*128+t];
    out[10880 + g*128 + t] = s;
  }
}

__global__ void k_sentinel(float* out, float code){
  out[0] = code;
}

extern "C" void kernel_launch(void* const* d_in, const int* in_sizes, int n_in,
                              void* d_out, int out_size, void* d_ws, size_t ws_size,
                              hipStream_t stream){
  const float* X    = (const float*)d_in[0];
  const int*  EI    = (const int*)d_in[1];
  const int*  batch = (const int*)d_in[2];
  const int* src = EI;
  const int* dst = EI + E_;

  int iW1,ib1,iWl,iWr,ibs,iWg,ias,iad,ibg,ipr,iWc,ibc,iWd1,ibd1,iWd2,ibd2;
  int ig1,ibe1,im1,iv1,ig2,ibe2,im2,iv2,ig3,ibe3,im3,iv3;
  if(n_in >= 31 && in_sizes[5] == 128){
    iW1=3; ib1=4; ig1=5; ibe1=6; im1=7; iv1=8;
    iWl=9; iWr=10; ibs=11; ig2=12; ibe2=13; im2=14; iv2=15;
    iWg=16; ias=17; iad=18; ibg=19; ig3=20; ibe3=21; im3=22; iv3=23;
    ipr=24; iWc=25; ibc=26; iWd1=27; ibd1=28; iWd2=29; ibd2=30;
  }else{
    iW1=3; ib1=4; iWl=5; iWr=6; ibs=7; iWg=8; ias=9; iad=10; ibg=11;
    ipr=12; iWc=13; ibc=14; iWd1=15; ibd1=16; iWd2=17; ibd2=18;
    ig1=19; ibe1=20; im1=21; iv1=22; ig2=23; ibe2=24; im2=25; iv2=26;
    ig3=27; ibe3=28; im3=29; iv3=30;
  }
  const float* W1 = (const float*)d_in[iW1];   const float* b1 = (const float*)d_in[ib1];
  const float* Wl = (const float*)d_in[iWl];   const float* Wr = (const float*)d_in[iWr];
  const float* bs = (const float*)d_in[ibs];   const float* Wg = (const float*)d_in[iWg];
  const float* a_src = (const float*)d_in[ias]; const float* a_dst = (const float*)d_in[iad];
  const float* bg = (const float*)d_in[ibg];   const float* protos = (const float*)d_in[ipr];
  const float* Wc = (const float*)d_in[iWc];   const float* bc = (const float*)d_in[ibc];
  const float* Wd1 = (const float*)d_in[iWd1]; const float* bd1 = (const float*)d_in[ibd1];
  const float* Wd2 = (const float*)d_in[iWd2]; const float* bd2 = (const float*)d_in[ibd2];
  const float* g1 = (const float*)d_in[ig1];   const float* be1 = (const float*)d_in[ibe1];
  const float* m1 = (const float*)d_in[im1];   const float* v1 = (const float*)d_in[iv1];
  const float* g2 = (const float*)d_in[ig2];   const float* be2 = (const float*)d_in[ibe2];
  const float* m2 = (const float*)d_in[im2];   const float* v2 = (const float*)d_in[iv2];
  const float* g3 = (const float*)d_in[ig3];   const float* be3 = (const float*)d_in[ibe3];
  const float* m3 = (const float*)d_in[im3];   const float* v3 = (const float*)d_in[iv3];

  const size_t NF = (size_t)N_*H_;
  // ints: cnt(N) + row_ptr(N+4) + tmp(N) + esrc(E) + bsum(64) + boff(64)
  const size_t intN = (size_t)3*N_ + 4 + (size_t)E_ + 128;
  // floats: dinv(N) + als4(4N) + ald4(4N) + pooled(G*H) + gcnt(G) + vs3(384) + vd3(384)
  const size_t fltN = (size_t)9*N_ + G_*H_ + G_ + 768;
  const size_t NEED = NF*2*3 + (size_t)N_*384*2 + intN*4 + fltN*4 + (size_t)6*16384*2;
  if(ws_size < NEED){
    k_sentinel<<<1,1,0,stream>>>((float*)d_out, 1000.f + (float)(ws_size>>20));
    return;
  }
  bf16* RA = (bf16*)d_ws;            // h -> h2
  bf16* RB = RA + NF;                // h1
  bf16* RC = RB + NF;                // mean_nb -> h3
  bf16* U  = RC + NF;                // N x 384 aggregated h2-space (3 heads)
  int*  cnt     = (int*)(U + (size_t)N_*384);
  int*  row_ptr = cnt + N_;
  int*  tmp     = row_ptr + (N_+4);
  int*  esrc    = tmp + N_;
  int*  bsum    = esrc + E_;
  int*  boff    = bsum + 64;
  float* dinv   = (float*)(boff + 64);
  float* als4   = dinv + N_;         // N*4 (16B-aligned)
  float* ald4   = als4 + (size_t)N_*4;
  float* pooled = ald4 + (size_t)N_*4;
  float* gcnt   = pooled + (size_t)G_*H_;
  float* vs3    = gcnt + G_;
  float* vd3    = vs3 + 384;
  unsigned short* WTg = (unsigned short*)(vd3 + 384);

  // ---- weight prep + CSR build ----
  k_wprep<<<(6*16384+255)/256, 256, 0, stream>>>(W1, Wl, Wr, Wg, WTg);
  k_vprep<<<1, 384, 0, stream>>>(Wg, a_src, a_dst, vs3, vd3);
  hipMemsetAsync(cnt, 0, N_*sizeof(int), stream);
  hipMemsetAsync(pooled, 0, (size_t)(G_*H_+G_)*sizeof(float), stream);
  k_count<<<(E_+255)/256, 256, 0, stream>>>(dst, cnt);
  k_scan1<<<NB_, 1024, 0, stream>>>(cnt, row_ptr, dinv, bsum);
  k_scan2<<<1, 64, 0, stream>>>(bsum, boff, row_ptr);
  k_scan3<<<(N_+255)/256, 256, 0, stream>>>(row_ptr, boff, tmp);
  k_scatter<<<(E_+255)/256, 256, 0, stream>>>(src, dst, tmp, esrc);

  const int MB = (N_+63)/64;
  // ---- GCN ----
  k_mm_x<<<MB, 256, 0, stream>>>(X, WTg, RA);
  k_gcn_gather<<<N_, 64, 0, stream>>>(row_ptr, esrc, dinv, RA, b1, g1, be1, m1, v1, RB);
  // ---- SAGE (+ fused GAT logits) ----
  k_sage_gather<<<N_, 64, 0, stream>>>(row_ptr, esrc, RB, RC);
  k_sage_mm_att<<<MB, 256, 0, stream>>>(RC, RB, WTg + 16384, WTg + 2*16384, bs, g2, be2, m2, v2,
                                        vs3, vd3, RA, als4, ald4);
  // ---- GAT: h2-space aggregation (edge weights fused), then one K=384 GEMM ----
  k_gat_agg<<<N_, 64, 0, stream>>>(row_ptr, esrc, als4, ald4, RA, U);
  k_gat_mm3<<<MB, 256, 0, stream>>>(U, WTg + 3*16384, bg, g3, be3, m3, v3, RC);
  // ---- pool + head ----
  {
    int waves = (N_ + NPW_ - 1)/NPW_;
    int blocks = (waves + 3)/4;
    k_h3pool<<<blocks, 256, 0, stream>>>(RC, batch, pooled, gcnt);
  }
  k_head<<<G_, 128, 0, stream>>>(pooled, gcnt, protos, Wc, bc, Wd1, bd1, Wd2, bd2, (float*)d_out);
}